// Round 11
// baseline (346.602 us; speedup 1.0000x reference)
//
#include <hip/hip_runtime.h>
#include <hip/hip_bf16.h>
#include <cstdint>
#include <cstddef>

#define BB 16384

typedef float  floatx4 __attribute__((ext_vector_type(4)));
typedef __bf16 bf16x8  __attribute__((ext_vector_type(8)));

__device__ __forceinline__ unsigned short f2bf(float f) {
  union { float f; unsigned int u; } v; v.f = f;
  unsigned int r = v.u + 0x7FFFu + ((v.u >> 16) & 1u);
  return (unsigned short)(r >> 16);
}
__device__ __forceinline__ float bf2f(unsigned short h) {
  union { unsigned int u; float f; } v; v.u = ((unsigned int)h) << 16;
  return v.f;
}
__device__ __forceinline__ float gelu_exact(float x) {
  return 0.5f * x * (1.0f + erff(x * 0.7071067811865475f));
}

// async global->LDS, 16B per lane; LDS dest = wave-uniform base + lane*16
#define ALOAD16(g, l) \
  __builtin_amdgcn_global_load_lds((const __attribute__((address_space(1))) void*)(g), \
                                   (__attribute__((address_space(3))) void*)(l), 16, 0, 0)

// ---------------------------------------------------------------------------
// k_pack: wallt2 (144x128: W cols + q1/q2 fused ei/ej cols + zero pad)
//         + item_mm vec4 + item_emb vec4
// ---------------------------------------------------------------------------
__global__ void k_pack(const float* __restrict__ gnn_W, const float* __restrict__ gnn_a,
                       const float* __restrict__ item_mm, const float* __restrict__ item_emb,
                       unsigned short* __restrict__ wallt2, unsigned short* __restrict__ immb,
                       unsigned short* __restrict__ iembb)
{
  const int total = 18432 + 524288 + 2934976;
  for (int id = blockIdx.x * 256 + threadIdx.x; id < total; id += gridDim.x * 256) {
    if (id < 18432) {                  // wallt2[n][k], n < 144
      int n = id / 128, k = id % 128;
      if (n < 128) {
        wallt2[id] = f2bf(gnn_W[(n >> 5) * 4096 + k * 32 + (n & 31)]);
      } else if (n < 136) {            // q1 (n=128..131) / q2 (n=132..135)
        int h = (n - 128) & 3;
        int off = (n < 132) ? 0 : 32;
        float s = 0.f;
        for (int o = 0; o < 32; o++)
          s += gnn_W[h * 4096 + k * 32 + o] * gnn_a[h * 64 + off + o];
        wallt2[id] = f2bf(s);
      } else {
        wallt2[id] = 0;
      }
    } else if (id < 542720) {          // item_mm cvt vec4
      int l = id - 18432;
      float4 v = ((const float4*)item_mm)[l];
      ushort4 o; o.x = f2bf(v.x); o.y = f2bf(v.y); o.z = f2bf(v.z); o.w = f2bf(v.w);
      ((ushort4*)immb)[l] = o;
    } else {                           // item_emb cvt vec4
      int l = id - 542720;
      float4 v = ((const float4*)item_emb)[l];
      ushort4 o; o.x = f2bf(v.x); o.y = f2bf(v.y); o.z = f2bf(v.z); o.w = f2bf(v.w);
      ((ushort4*)iembb)[l] = o;
    }
  }
}

// ---------------------------------------------------------------------------
// Merged LDS-tiled transposes (fp32 in, bf16^T out)
// ---------------------------------------------------------------------------
__global__ __launch_bounds__(256)
void k_transp2(const float* __restrict__ w1, const float* __restrict__ w2,
               const float* __restrict__ bi_W, const float* __restrict__ mm_w,
               unsigned short* __restrict__ w1t, unsigned short* __restrict__ w2t,
               unsigned short* __restrict__ biwt, unsigned short* __restrict__ mmwt)
{
  __shared__ float tile[64][65];
  int blk = blockIdx.x;
  const float* in; unsigned short* outp; int R, C, bx, by;
  if (blk < 336)      { in = w1; outp = w1t; R = 2688; C = 512; bx = blk % 8; by = blk / 8; }
  else if (blk < 368) { blk -= 336; in = w2; outp = w2t; R = 512; C = 256; bx = blk % 4; by = blk / 4; }
  else if (blk < 388) { blk -= 368; int f = blk / 4; int r2 = blk % 4;
                        in = bi_W + f * 16384; outp = biwt + f * 16384;
                        R = 128; C = 128; bx = r2 % 2; by = r2 / 2; }
  else                { blk -= 388; in = mm_w; outp = mmwt; R = 128; C = 128;
                        bx = blk % 2; by = blk / 2; }
  const int c0 = bx * 64, r0 = by * 64;
  const int lr = threadIdx.x >> 6;
  const int lc = threadIdx.x & 63;
  #pragma unroll
  for (int i = 0; i < 16; i++) {
    int r = lr + i * 4;
    tile[r][lc] = in[(size_t)(r0 + r) * C + c0 + lc];
  }
  __syncthreads();
  #pragma unroll
  for (int i = 0; i < 16; i++) {
    int c = lr + i * 4;
    outp[(size_t)(c0 + c) * R + r0 + lc] = f2bf(tile[lc][c]);
  }
}

// ---------------------------------------------------------------------------
// MLP1 GEMM: h1 = gelu(bn1(c @ w1 + b1)).  128x128 tile, BK=64, 512 thr,
// 8 waves 2x4 (per-wave 64x32).  XOR-8 swizzled global_load_lds staging.
// REVERTED to R5's BK=64 structure: measured 0 bank conflicts / 54.8 us.
// (BK=128 variant measured SQ_LDS_BANK_CONFLICT=8.26e6 @ 69.2 us - R10.)
// ---------------------------------------------------------------------------
__global__ __launch_bounds__(512)
void gemm_mlp1(const unsigned short* __restrict__ A, const unsigned short* __restrict__ Bt,
               unsigned short* __restrict__ Cp,
               const float* __restrict__ bias, const float* __restrict__ bng,
               const float* __restrict__ bnb)
{
  int p = blockIdx.y * gridDim.x + blockIdx.x;
  int xcd = p & 7, slot = p >> 3;
  const int bx = slot % gridDim.x;
  const int by = xcd * (gridDim.y >> 3) + slot / gridDim.x;
  const int n0 = bx * 128;
  const int m0 = by * 128;

  __shared__ __align__(16) unsigned short As[128 * 64];   // 16 KB
  __shared__ __align__(16) unsigned short Bs[128 * 64];   // 16 KB
  const int t = threadIdx.x, lane = t & 63, w = t >> 6;
  const int wm = w & 1, wn = w >> 1;          // 2 x 4
  const int lr = lane & 15, lq = lane >> 4;

  floatx4 acc[4][2];
  #pragma unroll
  for (int a = 0; a < 4; a++)
    #pragma unroll
    for (int b = 0; b < 2; b++) acc[a][b] = (floatx4){0.f, 0.f, 0.f, 0.f};

  // staging: concat rows [A 0..128) [B 0..128), 8 rows per ALOAD16 issue,
  // 4 issues/wave.  lane -> (srow = lane>>3, phys chunk = lane&7);
  // slot (row, pc) holds logical chunk pc ^ (row&7)  [row&7 == srow here].
  const int srow = lane >> 3;
  const int schk = (lane & 7) ^ srow;
  const int rb0 = w * 32;

  for (int k0 = 0; k0 < 2688; k0 += 64) {
    __syncthreads();
    #pragma unroll
    for (int q = 0; q < 4; q++) {
      const int rb = rb0 + q * 8;
      if (rb < 128) {
        ALOAD16(A + (size_t)(m0 + rb + srow) * 2688 + k0 + schk * 8, As + rb * 64);
      } else {
        ALOAD16(Bt + (size_t)(n0 + rb - 128 + srow) * 2688 + k0 + schk * 8, Bs + (rb - 128) * 64);
      }
    }
    __syncthreads();
    #pragma unroll
    for (int ko = 0; ko < 2; ko++) {
      bf16x8 af[4], bfv[2];
      #pragma unroll
      for (int mt = 0; mt < 4; mt++) {
        const int row = wm * 64 + mt * 16 + lr;
        const int pc = (ko * 4 + lq) ^ (lr & 7);
        af[mt] = __builtin_bit_cast(bf16x8, *(const uint4*)&As[row * 64 + pc * 8]);
      }
      #pragma unroll
      for (int nt = 0; nt < 2; nt++) {
        const int row = wn * 32 + nt * 16 + lr;
        const int pc = (ko * 4 + lq) ^ (lr & 7);
        bfv[nt] = __builtin_bit_cast(bf16x8, *(const uint4*)&Bs[row * 64 + pc * 8]);
      }
      #pragma unroll
      for (int mt = 0; mt < 4; mt++)
        #pragma unroll
        for (int nt = 0; nt < 2; nt++)
          acc[mt][nt] = __builtin_amdgcn_mfma_f32_16x16x32_bf16(af[mt], bfv[nt], acc[mt][nt], 0, 0, 0);
    }
  }

  #pragma unroll
  for (int mt = 0; mt < 4; mt++)
    #pragma unroll
    for (int nt = 0; nt < 2; nt++)
      #pragma unroll
      for (int i = 0; i < 4; i++) {
        const int cm = m0 + wm * 64 + mt * 16 + lq * 4 + i;
        const int cn = n0 + wn * 32 + nt * 16 + lr;
        float tt = acc[mt][nt][i] + bias[cn];
        tt = tt * (bng[cn] * 0.9999950000374997f) + bnb[cn];
        Cp[(size_t)cm * 512 + cn] = f2bf(gelu_exact(tt));
      }
}

// ---------------------------------------------------------------------------
// Fused: y = item_mm @ mm_w + b -> LayerNorm -> GELU -> xb row 4.
// ---------------------------------------------------------------------------
__global__ __launch_bounds__(512)
void k_mmln(const unsigned short* __restrict__ A, const unsigned short* __restrict__ Bt,
            const float* __restrict__ mm_b, const float* __restrict__ ln_g,
            const float* __restrict__ ln_b, unsigned short* __restrict__ xb)
{
  __shared__ __align__(16) char smem[64 * 130 * 4];
  unsigned short* As = (unsigned short*)smem;
  unsigned short* Bs = (unsigned short*)(smem + 8192);
  float* cls = (float*)smem;

  const int t = threadIdx.x, lane = t & 63, w = t >> 6;
  const int lr = lane & 15, lq = lane >> 4;
  const int m0 = blockIdx.x * 64;

  floatx4 acc[4];
  #pragma unroll
  for (int a = 0; a < 4; a++) acc[a] = (floatx4){0.f, 0.f, 0.f, 0.f};

  const int srow = lane >> 3;
  const int schk = (lane & 7) ^ srow;
  const int rb0 = w * 24;

  for (int k0 = 0; k0 < 128; k0 += 64) {
    __syncthreads();
    #pragma unroll
    for (int q = 0; q < 3; q++) {
      const int rb = rb0 + q * 8;
      if (rb < 64) ALOAD16(A + (size_t)(m0 + rb + srow) * 128 + k0 + schk * 8, As + rb * 64);
      else { const int rbb = rb - 64; ALOAD16(Bt + (size_t)(rbb + srow) * 128 + k0 + schk * 8, Bs + rbb * 64); }
    }
    __syncthreads();
    #pragma unroll
    for (int ko = 0; ko < 2; ko++) {
      bf16x8 af[4], bv;
      #pragma unroll
      for (int mt = 0; mt < 4; mt++) {
        const int row = mt * 16 + lr;
        const int pc = (ko * 4 + lq) ^ (lr & 7);
        af[mt] = __builtin_bit_cast(bf16x8, *(const uint4*)&As[row * 64 + pc * 8]);
      }
      {
        const int row = w * 16 + lr;
        const int pc = (ko * 4 + lq) ^ (lr & 7);
        bv = __builtin_bit_cast(bf16x8, *(const uint4*)&Bs[row * 64 + pc * 8]);
      }
      #pragma unroll
      for (int mt = 0; mt < 4; mt++)
        acc[mt] = __builtin_amdgcn_mfma_f32_16x16x32_bf16(af[mt], bv, acc[mt], 0, 0, 0);
    }
  }

  __syncthreads();
  #pragma unroll
  for (int mt = 0; mt < 4; mt++)
    #pragma unroll
    for (int i = 0; i < 4; i++) {
      const int rr = mt * 16 + lq * 4 + i;
      const int cc = w * 16 + lr;
      cls[rr * 130 + cc] = acc[mt][i] + mm_b[cc];
    }
  __syncthreads();

  const float2 g2 = *(const float2*)&ln_g[lane * 2];
  const float2 b2 = *(const float2*)&ln_b[lane * 2];
  #pragma unroll
  for (int rr = 0; rr < 8; rr++) {
    const int r = w * 8 + rr;
    float2 v = *(const float2*)&cls[r * 130 + lane * 2];
    float s = v.x + v.y, s2 = v.x * v.x + v.y * v.y;
    #pragma unroll
    for (int o = 32; o > 0; o >>= 1) { s += __shfl_xor(s, o, 64); s2 += __shfl_xor(s2, o, 64); }
    float mu  = s * (1.0f / 128.0f);
    float var = s2 * (1.0f / 128.0f) - mu * mu;
    float rs  = rsqrtf(var + 1e-5f);
    float t0 = gelu_exact((v.x - mu) * rs * g2.x + b2.x);
    float t1 = gelu_exact((v.y - mu) * rs * g2.y + b2.y);
    unsigned int pk = (unsigned int)f2bf(t0) | ((unsigned int)f2bf(t1) << 16);
    *(unsigned int*)&xb[(size_t)(m0 + r) * 768 + 512 + lane * 2] = pk;
  }
}

// ---------------------------------------------------------------------------
// Fused: hp GEMM (96x144x128, ei/ej as fused columns 128..135) -> GAT
// attention + ELU + SE -> c[:, :768], sb.  1024 blocks x 256 thr.
// Wave grid 2x2; 9 B-tiles covered by tid = wn + 2*nt (nt<5, nt<4 || wn==0).
// ---------------------------------------------------------------------------
__global__ __launch_bounds__(256)
void k_hpatt(const unsigned short* __restrict__ xb, const unsigned short* __restrict__ wallt2,
             const float* __restrict__ se_w1, const float* __restrict__ se_b1,
             const float* __restrict__ se_w2, const float* __restrict__ se_b2,
             unsigned short* __restrict__ c, unsigned short* __restrict__ sb)
{
  __shared__ __align__(16) char smem[30720];
  unsigned short* As = (unsigned short*)smem;            // 96*64  = 12288 B
  unsigned short* Bs = (unsigned short*)(smem + 12288);  // 144*64 = 18432 B
  unsigned short* hps = (unsigned short*)smem;           // 96*146 bf16 (alias)

  const int t = threadIdx.x, lane = t & 63, w = t >> 6;
  const int wm = w & 1, wn = w >> 1;                     // both in {0,1}
  const int lr = lane & 15, lq = lane >> 4;
  const int m0 = blockIdx.x * 96;

  floatx4 acc[3][5];
  #pragma unroll
  for (int a = 0; a < 3; a++)
    #pragma unroll
    for (int b = 0; b < 5; b++) acc[a][b] = (floatx4){0.f, 0.f, 0.f, 0.f};

  const int srow = lane >> 3;
  const int schk = (lane & 7) ^ srow;

  for (int k0 = 0; k0 < 128; k0 += 64) {
    __syncthreads();
    #pragma unroll
    for (int q = 0; q < 8; q++) {
      const int e = w + 4 * q;          // 30 issues: A rows 96 (12), B rows 144 (18)
      if (e < 30) {
        const int rb = e * 8;
        if (rb < 96) {
          ALOAD16(xb + (size_t)(m0 + rb + srow) * 128 + k0 + schk * 8, As + rb * 64);
        } else {
          const int rbb = rb - 96;
          ALOAD16(wallt2 + (size_t)(rbb + srow) * 128 + k0 + schk * 8, Bs + rbb * 64);
        }
      }
    }
    __syncthreads();
    #pragma unroll
    for (int ko = 0; ko < 2; ko++) {
      bf16x8 af[3];
      #pragma unroll
      for (int mt = 0; mt < 3; mt++) {
        const int row = wm * 48 + mt * 16 + lr;
        const int pc = (ko * 4 + lq) ^ (lr & 7);
        af[mt] = __builtin_bit_cast(bf16x8, *(const uint4*)&As[row * 64 + pc * 8]);
      }
      #pragma unroll
      for (int nt = 0; nt < 5; nt++) {
        if (nt < 4 || wn == 0) {
          const int tid = wn + 2 * nt;  // wn0: 0,2,4,6,8 ; wn1: 1,3,5,7
          const int row = tid * 16 + lr;
          const int pc = (ko * 4 + lq) ^ (lr & 7);
          bf16x8 bfv = __builtin_bit_cast(bf16x8, *(const uint4*)&Bs[row * 64 + pc * 8]);
          #pragma unroll
          for (int mt = 0; mt < 3; mt++)
            acc[mt][nt] = __builtin_amdgcn_mfma_f32_16x16x32_bf16(af[mt], bfv, acc[mt][nt], 0, 0, 0);
        }
      }
    }
  }

  __syncthreads();                     // staging dead; write bf16 hp tile (146 stride)
  #pragma unroll
  for (int mt = 0; mt < 3; mt++)
    #pragma unroll
    for (int nt = 0; nt < 5; nt++)
      if (nt < 4 || wn == 0) {
        const int tid = wn + 2 * nt;
        #pragma unroll
        for (int i = 0; i < 4; i++) {
          const int rr = wm * 48 + mt * 16 + lq * 4 + i;
          const int cc = tid * 16 + lr;
          hps[rr * 146 + cc] = f2bf(acc[mt][nt][i]);
        }
      }
  __syncthreads();

  const int hh = lane >> 4;            // head of col pair (2l, 2l+1)

  for (int it = 0; it < 4; it++) {
    const int lb = w * 4 + it;
    const int b = blockIdx.x * 16 + lb;
    const unsigned short* hb = hps + lb * 6 * 146;

    float2 vm[6];
    float ein[6], ejn[6];
    #pragma unroll
    for (int m = 0; m < 6; m++) {
      unsigned int pk = *(const unsigned int*)&hb[m * 146 + lane * 2];
      vm[m].x = bf2f((unsigned short)(pk & 0xFFFFu));
      vm[m].y = bf2f((unsigned short)(pk >> 16));
      ein[m] = bf2f(hb[m * 146 + 128 + hh]);
      ejn[m] = bf2f(hb[m * 146 + 132 + hh]);
    }

    float g0[6], g1[6], zz[6];
    #pragma unroll
    for (int n = 0; n < 6; n++) {
      float ev[6]; float mx = -1e30f;
      #pragma unroll
      for (int m = 0; m < 6; m++) {
        float e = ein[n] + ejn[m];
        e = e > 0.f ? e : 0.2f * e;
        ev[m] = e; mx = fmaxf(mx, e);
      }
      float ss = 0.f;
      #pragma unroll
      for (int m = 0; m < 6; m++) { ev[m] = __expf(ev[m] - mx); ss += ev[m]; }
      const float inv = 1.0f / ss;
      float hn0 = 0.f, hn1 = 0.f;
      #pragma unroll
      for (int m = 0; m < 6; m++) {
        const float a = ev[m] * inv;
        hn0 += a * vm[m].x; hn1 += a * vm[m].y;
      }
      unsigned int xp = *(const unsigned int*)&xb[(size_t)b * 768 + n * 128 + lane * 2];
      float A0 = hn0 + bf2f((unsigned short)(xp & 0xFFFFu));
      float A1 = hn1 + bf2f((unsigned short)(xp >> 16));
      A0 = A0 > 0.f ? A0 : __expf(A0) - 1.0f;     // ELU, fast exp
      A1 = A1 > 0.f ? A1 : __expf(A1) - 1.0f;
      g0[n] = A0; g1[n] = A1;
      float zacc = A0 + A1;
      #pragma unroll
      for (int o = 32; o > 0; o >>= 1) zacc += __shfl_xor(zacc, o, 64);
      zz[n] = zacc * (1.0f / 128.0f);
    }

    float rr3[3];
    #pragma unroll
    for (int j = 0; j < 3; j++) {
      float a = se_b1[j];
      #pragma unroll
      for (int n = 0; n < 6; n++) a += zz[n] * se_w1[n * 3 + j];
      rr3[j] = fmaxf(a, 0.f);
    }
    float wse[6];
    #pragma unroll
    for (int n = 0; n < 6; n++) {
      float a = se_b2[n];
      #pragma unroll
      for (int j = 0; j < 3; j++) a += rr3[j] * se_w2[j * 6 + n];
      wse[n] = 1.0f / (1.0f + __expf(-a));
    }

    #pragma unroll
    for (int n = 0; n < 6; n++) {
      unsigned int pc = (unsigned int)f2bf(g0[n]) | ((unsigned int)f2bf(g1[n]) << 16);
      unsigned int ps = (unsigned int)f2bf(g0[n] * wse[n]) | ((unsigned int)f2bf(g1[n] * wse[n]) << 16);
      *(unsigned int*)&c[(size_t)b * 2688 + n * 128 + lane * 2]  = pc;
      *(unsigned int*)&sb[(size_t)b * 768 + n * 128 + lane * 2]  = ps;
    }
  }
}

// ---------------------------------------------------------------------------
// vid GEMM + pairs, LDS-transposed epilogue (unchanged)
// ---------------------------------------------------------------------------
__global__ __launch_bounds__(256)
void gemm_vid(const unsigned short* __restrict__ sbb, const unsigned short* __restrict__ biwt,
              unsigned short* __restrict__ c)
{
  const int z = blockIdx.z;
  const int m0 = blockIdx.y * 128;
  __shared__ __align__(16) unsigned short smem[128 * 130];
  unsigned short* As = smem;
  unsigned short* Bs = smem + 8192;
  const int t = threadIdx.x;
  const int lane = t & 63, w = t >> 6;
  const int wm = w & 1, wn = w >> 1;
  const int lr = lane & 15, lq = lane >> 4;

  floatx4 acc[4][4];
  #pragma unroll
  for (int a = 0; a < 4; a++)
    #pragma unroll
    for (int b = 0; b < 4; b++) acc[a][b] = (floatx4){0.f, 0.f, 0.f, 0.f};

  const int srow = lane >> 3;
  const int schk = (lane & 7) ^ srow;
  const unsigned short* Ag = sbb + (size_t)(m0 + w * 32 + srow) * 768 + z * 128 + schk * 8;
  const unsigned short* Bg = biwt + z * 16384 + (size_t)(w * 32 + srow) * 128 + schk * 8;
  unsigned short* AsW = As + w * 32 * 64;
  unsigned short* BsW = Bs + w * 32 * 64;

  for (int k0 = 0; k0 < 128; k0 += 64) {
    __syncthreads();
    #pragma unroll
    for (int q = 0; q < 4; q++) {
      ALOAD16(Ag + k0 + (size_t)(q * 8) * 768, AsW + q * 512);
      ALOAD16(Bg + k0 + (size_t)(q * 8) * 128, BsW + q * 512);
    }
    __syncthreads();
    #pragma unroll
    for (int ko = 0; ko < 2; ko++) {
      bf16x8 af[4], bfv[4];
      #pragma unroll
      for (int mt = 0; mt < 4; mt++) {
        const int row = wm * 64 + mt * 16 + lr;
        const int pc = (ko * 4 + lq) ^ (lr & 7);
        af[mt] = __builtin_bit_cast(bf16x8, *(const uint4*)&As[row * 64 + pc * 8]);
      }
      #pragma unroll
      for (int nt = 0; nt < 4; nt++) {
        const int row = wn * 64 + nt * 16 + lr;
        const int pc = (ko * 4 + lq) ^ (lr & 7);
        bfv[nt] = __builtin_bit_cast(bf16x8, *(const uint4*)&Bs[row * 64 + pc * 8]);
      }
      #pragma unroll
      for (int mt = 0; mt < 4; mt++)
        #pragma unroll
        for (int nt = 0; nt < 4; nt++)
          acc[mt][nt] = __builtin_amdgcn_mfma_f32_16x16x32_bf16(af[mt], bfv[nt], acc[mt][nt], 0, 0, 0);
    }
  }

  __syncthreads();
  #pragma unroll
  for (int mt = 0; mt < 4; mt++)
    #pragma unroll
    for (int nt = 0; nt < 4; nt++)
      #pragma unroll
      for (int i = 0; i < 4; i++) {
        const int rr = wm * 64 + mt * 16 + lq * 4 + i;
        const int cc = wn * 64 + nt * 16 + lr;
        smem[rr * 130 + cc] = f2bf(acc[mt][nt][i]);
      }
  __syncthreads();

  const int pb0[5] = {0, 5, 9, 12, 14};
  const int npairs = 5 - z;
  const int tot = 128 * 32 * npairs;
  for (int e = t; e < tot; e += 256) {
    const int g  = e & 31;
    const int rp = e >> 5;
    const int p  = rp % npairs;
    const int r  = rp / npairs;
    ushort4 vv = *(const ushort4*)&smem[r * 130 + g * 4];
    ushort4 sv = *(const ushort4*)&sbb[(size_t)(m0 + r) * 768 + (z + 1 + p) * 128 + g * 4];
    ushort4 o;
    o.x = f2bf(bf2f(vv.x) * bf2f(sv.x));
    o.y = f2bf(bf2f(vv.y) * bf2f(sv.y));
    o.z = f2bf(bf2f(vv.z) * bf2f(sv.z));
    o.w = f2bf(bf2f(vv.w) * bf2f(sv.w));
    *(ushort4*)&c[(size_t)(m0 + r) * 2688 + 768 + (size_t)(pb0[z] + p) * 128 + g * 4] = o;
  }
}

// ---------------------------------------------------------------------------
// Feature build: rows 0,1,2,3,5 (unchanged)
// ---------------------------------------------------------------------------
__global__ __launch_bounds__(256)
void k_feat(const int* __restrict__ item_id, const int* __restrict__ likes,
            const int* __restrict__ views, const int* __restrict__ item_seq,
            const unsigned short* __restrict__ iembb, const float* __restrict__ cate_emb,
            unsigned short* __restrict__ xb)
{
  const int b = blockIdx.x * 4 + (threadIdx.x >> 6);
  const int lane = threadIdx.x & 63;
  const int half = lane >> 5, ql = lane & 31;
  const size_t base = (size_t)b * 768;
  const int li = likes[b], vi = views[b], id = item_id[b];

  int idxs[25];
  #pragma unroll
  for (int j = 0; j < 25; j++) idxs[j] = item_seq[b * 50 + half + 2 * j];

  float4 hs = make_float4(0.f, 0.f, 0.f, 0.f);
  float cnt = 0.f;
  #pragma unroll
  for (int j = 0; j < 25; j++) {
    const int idx = idxs[j];
    if (idx != 0) {
      cnt += 1.0f;
      ushort4 v = *(const ushort4*)&iembb[(size_t)idx * 128 + ql * 4];
      hs.x += bf2f(v.x); hs.y += bf2f(v.y); hs.z += bf2f(v.z); hs.w += bf2f(v.w);
    }
  }
  cnt  += __shfl_xor(cnt, 32, 64);
  hs.x += __shfl_xor(hs.x, 32, 64);
  hs.y += __shfl_xor(hs.y, 32, 64);
  hs.z += __shfl_xor(hs.z, 32, 64);
  hs.w += __shfl_xor(hs.w, 32, 64);
  const float ic = 1.0f / fmaxf(cnt, 1.0f);

  *(unsigned int*)&xb[base + lane * 2] = 0u;

  {
    const float4 v = *(const float4*)&cate_emb[(size_t)(half ? vi : li) * 128 + ql * 4];
    ushort4 o; o.x = f2bf(v.x); o.y = f2bf(v.y); o.z = f2bf(v.z); o.w = f2bf(v.w);
    *(ushort4*)&xb[base + 128 + half * 128 + ql * 4] = o;
  }
  if (half == 0) {
    *(ushort4*)&xb[base + 384 + ql * 4] =
        *(const ushort4*)&iembb[(size_t)id * 128 + ql * 4];
  } else {
    ushort4 o; o.x = f2bf(hs.x * ic); o.y = f2bf(hs.y * ic);
               o.z = f2bf(hs.z * ic); o.w = f2bf(hs.w * ic);
    *(ushort4*)&xb[base + 640 + ql * 4] = o;
  }
}

// ---------------------------------------------------------------------------
// Fused MLP2 + bn+gelu + final 256-dot + sigmoid -> out
// ---------------------------------------------------------------------------
__global__ __launch_bounds__(512)
void k_mlp2out(const unsigned short* __restrict__ A, const unsigned short* __restrict__ Bt,
               const float* __restrict__ b2v, const float* __restrict__ bng,
               const float* __restrict__ bnb, const float* __restrict__ w3,
               const float* __restrict__ b3, float* __restrict__ out)
{
  __shared__ __align__(16) char smem[40960];
  unsigned short* As = (unsigned short*)smem;
  unsigned short* Bs = (unsigned short*)(smem + 8192);
  unsigned short* h2s = (unsigned short*)smem;

  const int t = threadIdx.x, lane = t & 63, w = t >> 6;
  const int lr = lane & 15, lq = lane >> 4;
  const int m0 = blockIdx.x * 64;

  floatx4 acc[4][2];
  #pragma unroll
  for (int a = 0; a < 4; a++)
    #pragma unroll
    for (int b = 0; b < 2; b++) acc[a][b] = (floatx4){0.f, 0.f, 0.f, 0.f};

  const int srow = lane >> 3;
  const int schk = (lane & 7) ^ srow;
  const int rb0 = w * 40;

  for (int k0 = 0; k0 < 512; k0 += 64) {
    __syncthreads();
    #pragma unroll
    for (int q = 0; q < 5; q++) {
      const int rb = rb0 + q * 8;
      if (rb < 64) ALOAD16(A + (size_t)(m0 + rb + srow) * 512 + k0 + schk * 8, As + rb * 64);
      else { const int rbb = rb - 64; ALOAD16(Bt + (size_t)(rbb + srow) * 512 + k0 + schk * 8, Bs + rbb * 64); }
    }
    __syncthreads();
    #pragma unroll
    for (int ko = 0; ko < 2; ko++) {
      bf16x8 af[4], bfv[2];
      #pragma unroll
      for (int mt = 0; mt < 4; mt++) {
        const int row = mt * 16 + lr;
        const int pc = (ko * 4 + lq) ^ (lr & 7);
        af[mt] = __builtin_bit_cast(bf16x8, *(const uint4*)&As[row * 64 + pc * 8]);
      }
      #pragma unroll
      for (int nt = 0; nt < 2; nt++) {
        const int row = w * 32 + nt * 16 + lr;
        const int pc = (ko * 4 + lq) ^ (lr & 7);
        bfv[nt] = __builtin_bit_cast(bf16x8, *(const uint4*)&Bs[row * 64 + pc * 8]);
      }
      #pragma unroll
      for (int mt = 0; mt < 4; mt++)
        #pragma unroll
        for (int nt = 0; nt < 2; nt++)
          acc[mt][nt] = __builtin_amdgcn_mfma_f32_16x16x32_bf16(af[mt], bfv[nt], acc[mt][nt], 0, 0, 0);
    }
  }

  __syncthreads();
  #pragma unroll
  for (int mt = 0; mt < 4; mt++)
    #pragma unroll
    for (int nt = 0; nt < 2; nt++)
      #pragma unroll
      for (int i = 0; i < 4; i++) {
        const int rr = mt * 16 + lq * 4 + i;
        const int cc = w * 32 + nt * 16 + lr;
        float tt = acc[mt][nt][i] + b2v[cc];
        tt = tt * (bng[cc] * 0.9999950000374997f) + bnb[cc];
        h2s[rr * 264 + cc] = f2bf(gelu_exact(tt));
      }
  __syncthreads();

  const float4 w4 = *(const float4*)&w3[lane * 4];
  #pragma unroll
  for (int rr = 0; rr < 8; rr++) {
    const int r = w * 8 + rr;
    ushort4 v = *(const ushort4*)&h2s[r * 264 + lane * 4];
    float a = bf2f(v.x) * w4.x + bf2f(v.y) * w4.y + bf2f(v.z) * w4.z + bf2f(v.w) * w4.w;
    #pragma unroll
    for (int o = 32; o > 0; o >>= 1) a += __shfl_xor(a, o, 64);
    if (lane == 0) out[m0 + r] = 1.0f / (1.0f + __expf(-(a + b3[0])));
  }
}

// ---------------------------------------------------------------------------
// Workspace layout (bytes).  Peak ~203 MB (+ wallt2 at tail).
// ---------------------------------------------------------------------------
#define OFF_MMWT   0ull           // 32768
#define OFF_BIWT   65536ull       // 163840
#define OFF_W1T    229376ull      // 2752512
#define OFF_W2T    2981888ull     // 262144
#define OFF_IMMB   3244032ull     // 4194304
#define OFF_XB     7438336ull     // 25165824  (alias: h1 later)
#define OFF_SB     57769984ull    // 25165824
#define OFF_C      82935808ull    // 88080384
#define OFF_IEMB   179404800ull   // 23479808
#define OFF_WALLT2 202884608ull   // 36864 -> total 202921472

extern "C" void kernel_launch(void* const* d_in, const int* in_sizes, int n_in,
                              void* d_out, int out_size, void* d_ws, size_t ws_size,
                              hipStream_t stream)
{
  const int*   item_id  = (const int*)  d_in[0];
  const float* item_mm  = (const float*)d_in[1];
  const int*   likes    = (const int*)  d_in[2];
  const int*   views    = (const int*)  d_in[3];
  const int*   item_seq = (const int*)  d_in[4];
  const float* item_emb = (const float*)d_in[5];
  const float* cate_emb = (const float*)d_in[6];
  const float* mm_w     = (const float*)d_in[7];
  const float* mm_b     = (const float*)d_in[8];
  const float* ln_g     = (const float*)d_in[9];
  const float* ln_b     = (const float*)d_in[10];
  const float* gnn_W    = (const float*)d_in[11];
  const float* gnn_a    = (const float*)d_in[12];
  const float* se_w1    = (const float*)d_in[13];
  const float* se_b1    = (const float*)d_in[14];
  const float* se_w2    = (const float*)d_in[15];
  const float* se_b2    = (const float*)d_in[16];
  const float* bi_W     = (const float*)d_in[17];
  const float* mlp_w1   = (const float*)d_in[18];
  const float* mlp_b1   = (const float*)d_in[19];
  const float* bn1_g    = (const float*)d_in[20];
  const float* bn1_b    = (const float*)d_in[21];
  const float* mlp_w2   = (const float*)d_in[22];
  const float* mlp_b2   = (const float*)d_in[23];
  const float* bn2_g    = (const float*)d_in[24];
  const float* bn2_b    = (const float*)d_in[25];
  const float* mlp_w3   = (const float*)d_in[26];
  const float* mlp_b3   = (const float*)d_in[27];
  float* out = (float*)d_out;

  char* ws = (char*)d_ws;
  unsigned short* mmwt   = (unsigned short*)(ws + OFF_MMWT);
  unsigned short* biwt   = (unsigned short*)(ws + OFF_BIWT);
  unsigned short* w1t    = (unsigned short*)(ws + OFF_W1T);
  unsigned short* w2t    = (unsigned short*)(ws + OFF_W2T);
  unsigned short* immb   = (unsigned short*)(ws + OFF_IMMB);
  unsigned short* xb     = (unsigned short*)(ws + OFF_XB);
  unsigned short* sbb    = (unsigned short*)(ws + OFF_SB);
  unsigned short* cbuf   = (unsigned short*)(ws + OFF_C);
  unsigned short* h1b    = (unsigned short*)(ws + OFF_XB);   // alias: xb dead after k_hpatt
  unsigned short* iembb  = (unsigned short*)(ws + OFF_IEMB);
  unsigned short* wallt2 = (unsigned short*)(ws + OFF_WALLT2);

  // 1. packs (wallt2 with fused ei/ej cols + item_mm/item_emb vec4 converts)
  k_pack<<<4096, 256, 0, stream>>>(gnn_W, gnn_a, item_mm, item_emb, wallt2, immb, iembb);
  // 2. merged LDS-tiled transposes: w1, w2, bi_W, mm_w
  k_transp2<<<392, 256, 0, stream>>>(mlp_w1, mlp_w2, bi_W, mm_w, w1t, w2t, biwt, mmwt);
  // 3. feature rows 0,1,2,3,5
  k_feat<<<BB / 4, 256, 0, stream>>>(item_id, likes, views, item_seq, iembb, cate_emb, xb);
  // 4. fused mm GEMM + bias + LN + GELU -> xb row 4
  k_mmln<<<256, 512, 0, stream>>>(immb, mmwt, mm_b, ln_g, ln_b, xb);
  // 5. fused hp GEMM (ei/ej in-GEMM) + attention + SE -> c[:, :768], sb
  k_hpatt<<<1024, 256, 0, stream>>>(xb, wallt2, se_w1, se_b1, se_w2, se_b2, cbuf, sbb);
  // 6. vid GEMM + pairs -> c[:, 768:]
  gemm_vid<<<dim3(1, 128, 5), 256, 0, stream>>>(sbb, biwt, cbuf);
  // 7. MLP1: h1 = gelu(bn1(c @ w1 + b1)), BK=64 (0-conflict layout, R5-proven)
  gemm_mlp1<<<dim3(4, 128), 512, 0, stream>>>(cbuf, w1t, h1b, mlp_b1, bn1_g, bn1_b);
  // 8. fused MLP2 + bn + gelu + dot(w3) + sigmoid -> out
  k_mlp2out<<<256, 512, 0, stream>>>(h1b, w2t, mlp_b2, bn2_g, bn2_b, mlp_w3, mlp_b3, out);
}

// Round 12
// 333.321 us; speedup vs baseline: 1.0398x; 1.0398x over previous
//
#include <hip/hip_runtime.h>
#include <hip/hip_bf16.h>
#include <cstdint>
#include <cstddef>

#define BB 16384

typedef float  floatx4 __attribute__((ext_vector_type(4)));
typedef __bf16 bf16x8  __attribute__((ext_vector_type(8)));

__device__ __forceinline__ unsigned short f2bf(float f) {
  union { float f; unsigned int u; } v; v.f = f;
  unsigned int r = v.u + 0x7FFFu + ((v.u >> 16) & 1u);
  return (unsigned short)(r >> 16);
}
__device__ __forceinline__ float bf2f(unsigned short h) {
  union { unsigned int u; float f; } v; v.u = ((unsigned int)h) << 16;
  return v.f;
}
__device__ __forceinline__ float gelu_exact(float x) {
  return 0.5f * x * (1.0f + erff(x * 0.7071067811865475f));
}

// async global->LDS, 16B per lane; LDS dest = wave-uniform base + lane*16
#define ALOAD16(g, l) \
  __builtin_amdgcn_global_load_lds((const __attribute__((address_space(1))) void*)(g), \
                                   (__attribute__((address_space(3))) void*)(l), 16, 0, 0)

// ---------------------------------------------------------------------------
// k_pack: wallt2 (144x128: W cols + q1/q2 fused ei/ej cols + zero pad)
//         + item_mm vec4 + item_emb vec4
// ---------------------------------------------------------------------------
__global__ void k_pack(const float* __restrict__ gnn_W, const float* __restrict__ gnn_a,
                       const float* __restrict__ item_mm, const float* __restrict__ item_emb,
                       unsigned short* __restrict__ wallt2, unsigned short* __restrict__ immb,
                       unsigned short* __restrict__ iembb)
{
  const int total = 18432 + 524288 + 2934976;
  for (int id = blockIdx.x * 256 + threadIdx.x; id < total; id += gridDim.x * 256) {
    if (id < 18432) {                  // wallt2[n][k], n < 144
      int n = id / 128, k = id % 128;
      if (n < 128) {
        wallt2[id] = f2bf(gnn_W[(n >> 5) * 4096 + k * 32 + (n & 31)]);
      } else if (n < 136) {            // q1 (n=128..131) / q2 (n=132..135)
        int h = (n - 128) & 3;
        int off = (n < 132) ? 0 : 32;
        float s = 0.f;
        for (int o = 0; o < 32; o++)
          s += gnn_W[h * 4096 + k * 32 + o] * gnn_a[h * 64 + off + o];
        wallt2[id] = f2bf(s);
      } else {
        wallt2[id] = 0;
      }
    } else if (id < 542720) {          // item_mm cvt vec4
      int l = id - 18432;
      float4 v = ((const float4*)item_mm)[l];
      ushort4 o; o.x = f2bf(v.x); o.y = f2bf(v.y); o.z = f2bf(v.z); o.w = f2bf(v.w);
      ((ushort4*)immb)[l] = o;
    } else {                           // item_emb cvt vec4
      int l = id - 542720;
      float4 v = ((const float4*)item_emb)[l];
      ushort4 o; o.x = f2bf(v.x); o.y = f2bf(v.y); o.z = f2bf(v.z); o.w = f2bf(v.w);
      ((ushort4*)iembb)[l] = o;
    }
  }
}

// ---------------------------------------------------------------------------
// Merged LDS-tiled transposes (fp32 in, bf16^T out)
// ---------------------------------------------------------------------------
__global__ __launch_bounds__(256)
void k_transp2(const float* __restrict__ w1, const float* __restrict__ w2,
               const float* __restrict__ bi_W, const float* __restrict__ mm_w,
               unsigned short* __restrict__ w1t, unsigned short* __restrict__ w2t,
               unsigned short* __restrict__ biwt, unsigned short* __restrict__ mmwt)
{
  __shared__ float tile[64][65];
  int blk = blockIdx.x;
  const float* in; unsigned short* outp; int R, C, bx, by;
  if (blk < 336)      { in = w1; outp = w1t; R = 2688; C = 512; bx = blk % 8; by = blk / 8; }
  else if (blk < 368) { blk -= 336; in = w2; outp = w2t; R = 512; C = 256; bx = blk % 4; by = blk / 4; }
  else if (blk < 388) { blk -= 368; int f = blk / 4; int r2 = blk % 4;
                        in = bi_W + f * 16384; outp = biwt + f * 16384;
                        R = 128; C = 128; bx = r2 % 2; by = r2 / 2; }
  else                { blk -= 388; in = mm_w; outp = mmwt; R = 128; C = 128;
                        bx = blk % 2; by = blk / 2; }
  const int c0 = bx * 64, r0 = by * 64;
  const int lr = threadIdx.x >> 6;
  const int lc = threadIdx.x & 63;
  #pragma unroll
  for (int i = 0; i < 16; i++) {
    int r = lr + i * 4;
    tile[r][lc] = in[(size_t)(r0 + r) * C + c0 + lc];
  }
  __syncthreads();
  #pragma unroll
  for (int i = 0; i < 16; i++) {
    int c = lr + i * 4;
    outp[(size_t)(c0 + c) * R + r0 + lc] = f2bf(tile[lc][c]);
  }
}

// ---------------------------------------------------------------------------
// MLP1 GEMM: h1 = gelu(bn1(c @ w1 + b1)).  128x128 tile, BK=64, 512 thr,
// 8 waves 2x4.  XOR-8 swizzled global_load_lds staging (0-conflict layout).
// ---------------------------------------------------------------------------
__global__ __launch_bounds__(512)
void gemm_mlp1(const unsigned short* __restrict__ A, const unsigned short* __restrict__ Bt,
               unsigned short* __restrict__ Cp,
               const float* __restrict__ bias, const float* __restrict__ bng,
               const float* __restrict__ bnb)
{
  int p = blockIdx.y * gridDim.x + blockIdx.x;
  int xcd = p & 7, slot = p >> 3;
  const int bx = slot % gridDim.x;
  const int by = xcd * (gridDim.y >> 3) + slot / gridDim.x;
  const int n0 = bx * 128;
  const int m0 = by * 128;

  __shared__ __align__(16) unsigned short As[128 * 64];   // 16 KB
  __shared__ __align__(16) unsigned short Bs[128 * 64];   // 16 KB
  const int t = threadIdx.x, lane = t & 63, w = t >> 6;
  const int wm = w & 1, wn = w >> 1;          // 2 x 4
  const int lr = lane & 15, lq = lane >> 4;

  floatx4 acc[4][2];
  #pragma unroll
  for (int a = 0; a < 4; a++)
    #pragma unroll
    for (int b = 0; b < 2; b++) acc[a][b] = (floatx4){0.f, 0.f, 0.f, 0.f};

  const int srow = lane >> 3;
  const int schk = (lane & 7) ^ srow;
  const int rb0 = w * 32;

  for (int k0 = 0; k0 < 2688; k0 += 64) {
    __syncthreads();
    #pragma unroll
    for (int q = 0; q < 4; q++) {
      const int rb = rb0 + q * 8;
      if (rb < 128) {
        ALOAD16(A + (size_t)(m0 + rb + srow) * 2688 + k0 + schk * 8, As + rb * 64);
      } else {
        ALOAD16(Bt + (size_t)(n0 + rb - 128 + srow) * 2688 + k0 + schk * 8, Bs + (rb - 128) * 64);
      }
    }
    __syncthreads();
    #pragma unroll
    for (int ko = 0; ko < 2; ko++) {
      bf16x8 af[4], bfv[2];
      #pragma unroll
      for (int mt = 0; mt < 4; mt++) {
        const int row = wm * 64 + mt * 16 + lr;
        const int pc = (ko * 4 + lq) ^ (lr & 7);
        af[mt] = __builtin_bit_cast(bf16x8, *(const uint4*)&As[row * 64 + pc * 8]);
      }
      #pragma unroll
      for (int nt = 0; nt < 2; nt++) {
        const int row = wn * 32 + nt * 16 + lr;
        const int pc = (ko * 4 + lq) ^ (lr & 7);
        bfv[nt] = __builtin_bit_cast(bf16x8, *(const uint4*)&Bs[row * 64 + pc * 8]);
      }
      #pragma unroll
      for (int mt = 0; mt < 4; mt++)
        #pragma unroll
        for (int nt = 0; nt < 2; nt++)
          acc[mt][nt] = __builtin_amdgcn_mfma_f32_16x16x32_bf16(af[mt], bfv[nt], acc[mt][nt], 0, 0, 0);
    }
  }

  #pragma unroll
  for (int mt = 0; mt < 4; mt++)
    #pragma unroll
    for (int nt = 0; nt < 2; nt++)
      #pragma unroll
      for (int i = 0; i < 4; i++) {
        const int cm = m0 + wm * 64 + mt * 16 + lq * 4 + i;
        const int cn = n0 + wn * 32 + nt * 16 + lr;
        float tt = acc[mt][nt][i] + bias[cn];
        tt = tt * (bng[cn] * 0.9999950000374997f) + bnb[cn];
        Cp[(size_t)cm * 512 + cn] = f2bf(gelu_exact(tt));
      }
}

// ---------------------------------------------------------------------------
// Fused: y = item_mm @ mm_w + b -> LayerNorm -> GELU -> xb row 4.
// ---------------------------------------------------------------------------
__global__ __launch_bounds__(512)
void k_mmln(const unsigned short* __restrict__ A, const unsigned short* __restrict__ Bt,
            const float* __restrict__ mm_b, const float* __restrict__ ln_g,
            const float* __restrict__ ln_b, unsigned short* __restrict__ xb)
{
  __shared__ __align__(16) char smem[64 * 130 * 4];
  unsigned short* As = (unsigned short*)smem;
  unsigned short* Bs = (unsigned short*)(smem + 8192);
  float* cls = (float*)smem;

  const int t = threadIdx.x, lane = t & 63, w = t >> 6;
  const int lr = lane & 15, lq = lane >> 4;
  const int m0 = blockIdx.x * 64;

  floatx4 acc[4];
  #pragma unroll
  for (int a = 0; a < 4; a++) acc[a] = (floatx4){0.f, 0.f, 0.f, 0.f};

  const int srow = lane >> 3;
  const int schk = (lane & 7) ^ srow;
  const int rb0 = w * 24;

  for (int k0 = 0; k0 < 128; k0 += 64) {
    __syncthreads();
    #pragma unroll
    for (int q = 0; q < 3; q++) {
      const int rb = rb0 + q * 8;
      if (rb < 64) ALOAD16(A + (size_t)(m0 + rb + srow) * 128 + k0 + schk * 8, As + rb * 64);
      else { const int rbb = rb - 64; ALOAD16(Bt + (size_t)(rbb + srow) * 128 + k0 + schk * 8, Bs + rbb * 64); }
    }
    __syncthreads();
    #pragma unroll
    for (int ko = 0; ko < 2; ko++) {
      bf16x8 af[4], bv;
      #pragma unroll
      for (int mt = 0; mt < 4; mt++) {
        const int row = mt * 16 + lr;
        const int pc = (ko * 4 + lq) ^ (lr & 7);
        af[mt] = __builtin_bit_cast(bf16x8, *(const uint4*)&As[row * 64 + pc * 8]);
      }
      {
        const int row = w * 16 + lr;
        const int pc = (ko * 4 + lq) ^ (lr & 7);
        bv = __builtin_bit_cast(bf16x8, *(const uint4*)&Bs[row * 64 + pc * 8]);
      }
      #pragma unroll
      for (int mt = 0; mt < 4; mt++)
        acc[mt] = __builtin_amdgcn_mfma_f32_16x16x32_bf16(af[mt], bv, acc[mt], 0, 0, 0);
    }
  }

  __syncthreads();
  #pragma unroll
  for (int mt = 0; mt < 4; mt++)
    #pragma unroll
    for (int i = 0; i < 4; i++) {
      const int rr = mt * 16 + lq * 4 + i;
      const int cc = w * 16 + lr;
      cls[rr * 130 + cc] = acc[mt][i] + mm_b[cc];
    }
  __syncthreads();

  const float2 g2 = *(const float2*)&ln_g[lane * 2];
  const float2 b2 = *(const float2*)&ln_b[lane * 2];
  #pragma unroll
  for (int rr = 0; rr < 8; rr++) {
    const int r = w * 8 + rr;
    float2 v = *(const float2*)&cls[r * 130 + lane * 2];
    float s = v.x + v.y, s2 = v.x * v.x + v.y * v.y;
    #pragma unroll
    for (int o = 32; o > 0; o >>= 1) { s += __shfl_xor(s, o, 64); s2 += __shfl_xor(s2, o, 64); }
    float mu  = s * (1.0f / 128.0f);
    float var = s2 * (1.0f / 128.0f) - mu * mu;
    float rs  = rsqrtf(var + 1e-5f);
    float t0 = gelu_exact((v.x - mu) * rs * g2.x + b2.x);
    float t1 = gelu_exact((v.y - mu) * rs * g2.y + b2.y);
    unsigned int pk = (unsigned int)f2bf(t0) | ((unsigned int)f2bf(t1) << 16);
    *(unsigned int*)&xb[(size_t)(m0 + r) * 768 + 512 + lane * 2] = pk;
  }
}

// ---------------------------------------------------------------------------
// Fused: hp GEMM (96x144x128, ei/ej as fused columns 128..135) -> GAT
// attention + ELU + SE -> c[:, :768], sb.  1024 blocks x 256 thr.
// Wave grid 2x2; 9 B-tiles covered by tid = wn + 2*nt (nt<5, nt<4 || wn==0).
// ---------------------------------------------------------------------------
__global__ __launch_bounds__(256)
void k_hpatt(const unsigned short* __restrict__ xb, const unsigned short* __restrict__ wallt2,
             const float* __restrict__ se_w1, const float* __restrict__ se_b1,
             const float* __restrict__ se_w2, const float* __restrict__ se_b2,
             unsigned short* __restrict__ c, unsigned short* __restrict__ sb)
{
  __shared__ __align__(16) char smem[30720];
  unsigned short* As = (unsigned short*)smem;            // 96*64  = 12288 B
  unsigned short* Bs = (unsigned short*)(smem + 12288);  // 144*64 = 18432 B
  unsigned short* hps = (unsigned short*)smem;           // 96*146 bf16 (alias)

  const int t = threadIdx.x, lane = t & 63, w = t >> 6;
  const int wm = w & 1, wn = w >> 1;                     // both in {0,1}
  const int lr = lane & 15, lq = lane >> 4;
  const int m0 = blockIdx.x * 96;

  floatx4 acc[3][5];
  #pragma unroll
  for (int a = 0; a < 3; a++)
    #pragma unroll
    for (int b = 0; b < 5; b++) acc[a][b] = (floatx4){0.f, 0.f, 0.f, 0.f};

  const int srow = lane >> 3;
  const int schk = (lane & 7) ^ srow;

  for (int k0 = 0; k0 < 128; k0 += 64) {
    __syncthreads();
    #pragma unroll
    for (int q = 0; q < 8; q++) {
      const int e = w + 4 * q;          // 30 issues: A rows 96 (12), B rows 144 (18)
      if (e < 30) {
        const int rb = e * 8;
        if (rb < 96) {
          ALOAD16(xb + (size_t)(m0 + rb + srow) * 128 + k0 + schk * 8, As + rb * 64);
        } else {
          const int rbb = rb - 96;
          ALOAD16(wallt2 + (size_t)(rbb + srow) * 128 + k0 + schk * 8, Bs + rbb * 64);
        }
      }
    }
    __syncthreads();
    #pragma unroll
    for (int ko = 0; ko < 2; ko++) {
      bf16x8 af[3];
      #pragma unroll
      for (int mt = 0; mt < 3; mt++) {
        const int row = wm * 48 + mt * 16 + lr;
        const int pc = (ko * 4 + lq) ^ (lr & 7);
        af[mt] = __builtin_bit_cast(bf16x8, *(const uint4*)&As[row * 64 + pc * 8]);
      }
      #pragma unroll
      for (int nt = 0; nt < 5; nt++) {
        if (nt < 4 || wn == 0) {
          const int tid = wn + 2 * nt;  // wn0: 0,2,4,6,8 ; wn1: 1,3,5,7
          const int row = tid * 16 + lr;
          const int pc = (ko * 4 + lq) ^ (lr & 7);
          bf16x8 bfv = __builtin_bit_cast(bf16x8, *(const uint4*)&Bs[row * 64 + pc * 8]);
          #pragma unroll
          for (int mt = 0; mt < 3; mt++)
            acc[mt][nt] = __builtin_amdgcn_mfma_f32_16x16x32_bf16(af[mt], bfv, acc[mt][nt], 0, 0, 0);
        }
      }
    }
  }

  __syncthreads();                     // staging dead; write bf16 hp tile (146 stride)
  #pragma unroll
  for (int mt = 0; mt < 3; mt++)
    #pragma unroll
    for (int nt = 0; nt < 5; nt++)
      if (nt < 4 || wn == 0) {
        const int tid = wn + 2 * nt;
        #pragma unroll
        for (int i = 0; i < 4; i++) {
          const int rr = wm * 48 + mt * 16 + lq * 4 + i;
          const int cc = tid * 16 + lr;
          hps[rr * 146 + cc] = f2bf(acc[mt][nt][i]);
        }
      }
  __syncthreads();

  const int hh = lane >> 4;            // head of col pair (2l, 2l+1)

  for (int it = 0; it < 4; it++) {
    const int lb = w * 4 + it;
    const int b = blockIdx.x * 16 + lb;
    const unsigned short* hb = hps + lb * 6 * 146;

    float2 vm[6];
    float ein[6], ejn[6];
    #pragma unroll
    for (int m = 0; m < 6; m++) {
      unsigned int pk = *(const unsigned int*)&hb[m * 146 + lane * 2];
      vm[m].x = bf2f((unsigned short)(pk & 0xFFFFu));
      vm[m].y = bf2f((unsigned short)(pk >> 16));
      ein[m] = bf2f(hb[m * 146 + 128 + hh]);
      ejn[m] = bf2f(hb[m * 146 + 132 + hh]);
    }

    float g0[6], g1[6], zz[6];
    #pragma unroll
    for (int n = 0; n < 6; n++) {
      float ev[6]; float mx = -1e30f;
      #pragma unroll
      for (int m = 0; m < 6; m++) {
        float e = ein[n] + ejn[m];
        e = e > 0.f ? e : 0.2f * e;
        ev[m] = e; mx = fmaxf(mx, e);
      }
      float ss = 0.f;
      #pragma unroll
      for (int m = 0; m < 6; m++) { ev[m] = __expf(ev[m] - mx); ss += ev[m]; }
      const float inv = 1.0f / ss;
      float hn0 = 0.f, hn1 = 0.f;
      #pragma unroll
      for (int m = 0; m < 6; m++) {
        const float a = ev[m] * inv;
        hn0 += a * vm[m].x; hn1 += a * vm[m].y;
      }
      unsigned int xp = *(const unsigned int*)&xb[(size_t)b * 768 + n * 128 + lane * 2];
      float A0 = hn0 + bf2f((unsigned short)(xp & 0xFFFFu));
      float A1 = hn1 + bf2f((unsigned short)(xp >> 16));
      A0 = A0 > 0.f ? A0 : __expf(A0) - 1.0f;     // ELU, fast exp
      A1 = A1 > 0.f ? A1 : __expf(A1) - 1.0f;
      g0[n] = A0; g1[n] = A1;
      float zacc = A0 + A1;
      #pragma unroll
      for (int o = 32; o > 0; o >>= 1) zacc += __shfl_xor(zacc, o, 64);
      zz[n] = zacc * (1.0f / 128.0f);
    }

    float rr3[3];
    #pragma unroll
    for (int j = 0; j < 3; j++) {
      float a = se_b1[j];
      #pragma unroll
      for (int n = 0; n < 6; n++) a += zz[n] * se_w1[n * 3 + j];
      rr3[j] = fmaxf(a, 0.f);
    }
    float wse[6];
    #pragma unroll
    for (int n = 0; n < 6; n++) {
      float a = se_b2[n];
      #pragma unroll
      for (int j = 0; j < 3; j++) a += rr3[j] * se_w2[j * 6 + n];
      wse[n] = 1.0f / (1.0f + __expf(-a));
    }

    #pragma unroll
    for (int n = 0; n < 6; n++) {
      unsigned int pc = (unsigned int)f2bf(g0[n]) | ((unsigned int)f2bf(g1[n]) << 16);
      unsigned int ps = (unsigned int)f2bf(g0[n] * wse[n]) | ((unsigned int)f2bf(g1[n] * wse[n]) << 16);
      *(unsigned int*)&c[(size_t)b * 2688 + n * 128 + lane * 2]  = pc;
      *(unsigned int*)&sb[(size_t)b * 768 + n * 128 + lane * 2]  = ps;
    }
  }
}

// ---------------------------------------------------------------------------
// vid GEMM + pairs, LDS-transposed epilogue (unchanged)
// ---------------------------------------------------------------------------
__global__ __launch_bounds__(256)
void gemm_vid(const unsigned short* __restrict__ sbb, const unsigned short* __restrict__ biwt,
              unsigned short* __restrict__ c)
{
  const int z = blockIdx.z;
  const int m0 = blockIdx.y * 128;
  __shared__ __align__(16) unsigned short smem[128 * 130];
  unsigned short* As = smem;
  unsigned short* Bs = smem + 8192;
  const int t = threadIdx.x;
  const int lane = t & 63, w = t >> 6;
  const int wm = w & 1, wn = w >> 1;
  const int lr = lane & 15, lq = lane >> 4;

  floatx4 acc[4][4];
  #pragma unroll
  for (int a = 0; a < 4; a++)
    #pragma unroll
    for (int b = 0; b < 4; b++) acc[a][b] = (floatx4){0.f, 0.f, 0.f, 0.f};

  const int srow = lane >> 3;
  const int schk = (lane & 7) ^ srow;
  const unsigned short* Ag = sbb + (size_t)(m0 + w * 32 + srow) * 768 + z * 128 + schk * 8;
  const unsigned short* Bg = biwt + z * 16384 + (size_t)(w * 32 + srow) * 128 + schk * 8;
  unsigned short* AsW = As + w * 32 * 64;
  unsigned short* BsW = Bs + w * 32 * 64;

  for (int k0 = 0; k0 < 128; k0 += 64) {
    __syncthreads();
    #pragma unroll
    for (int q = 0; q < 4; q++) {
      ALOAD16(Ag + k0 + (size_t)(q * 8) * 768, AsW + q * 512);
      ALOAD16(Bg + k0 + (size_t)(q * 8) * 128, BsW + q * 512);
    }
    __syncthreads();
    #pragma unroll
    for (int ko = 0; ko < 2; ko++) {
      bf16x8 af[4], bfv[4];
      #pragma unroll
      for (int mt = 0; mt < 4; mt++) {
        const int row = wm * 64 + mt * 16 + lr;
        const int pc = (ko * 4 + lq) ^ (lr & 7);
        af[mt] = __builtin_bit_cast(bf16x8, *(const uint4*)&As[row * 64 + pc * 8]);
      }
      #pragma unroll
      for (int nt = 0; nt < 4; nt++) {
        const int row = wn * 64 + nt * 16 + lr;
        const int pc = (ko * 4 + lq) ^ (lr & 7);
        bfv[nt] = __builtin_bit_cast(bf16x8, *(const uint4*)&Bs[row * 64 + pc * 8]);
      }
      #pragma unroll
      for (int mt = 0; mt < 4; mt++)
        #pragma unroll
        for (int nt = 0; nt < 4; nt++)
          acc[mt][nt] = __builtin_amdgcn_mfma_f32_16x16x32_bf16(af[mt], bfv[nt], acc[mt][nt], 0, 0, 0);
    }
  }

  __syncthreads();
  #pragma unroll
  for (int mt = 0; mt < 4; mt++)
    #pragma unroll
    for (int nt = 0; nt < 4; nt++)
      #pragma unroll
      for (int i = 0; i < 4; i++) {
        const int rr = wm * 64 + mt * 16 + lq * 4 + i;
        const int cc = wn * 64 + nt * 16 + lr;
        smem[rr * 130 + cc] = f2bf(acc[mt][nt][i]);
      }
  __syncthreads();

  const int pb0[5] = {0, 5, 9, 12, 14};
  const int npairs = 5 - z;
  const int tot = 128 * 32 * npairs;
  for (int e = t; e < tot; e += 256) {
    const int g  = e & 31;
    const int rp = e >> 5;
    const int p  = rp % npairs;
    const int r  = rp / npairs;
    ushort4 vv = *(const ushort4*)&smem[r * 130 + g * 4];
    ushort4 sv = *(const ushort4*)&sbb[(size_t)(m0 + r) * 768 + (z + 1 + p) * 128 + g * 4];
    ushort4 o;
    o.x = f2bf(bf2f(vv.x) * bf2f(sv.x));
    o.y = f2bf(bf2f(vv.y) * bf2f(sv.y));
    o.z = f2bf(bf2f(vv.z) * bf2f(sv.z));
    o.w = f2bf(bf2f(vv.w) * bf2f(sv.w));
    *(ushort4*)&c[(size_t)(m0 + r) * 2688 + 768 + (size_t)(pb0[z] + p) * 128 + g * 4] = o;
  }
}

// ---------------------------------------------------------------------------
// Feature build, REWRITTEN: one wave per batch row; quarter-wave (16-lane)
// groups.  Lane loads 16 B (8 bf16) so 16 lanes cover a 256 B row — one
// wave-instruction gathers 4 rows (1 KB) vs 2 rows before (halved VMEM
// instruction count).  Group g handles seq entries j ≡ g (mod 4); outputs:
// g0 -> hist row 5, g1 -> id row 3, g2 -> like row 1, g3 -> view row 2.
// ---------------------------------------------------------------------------
__global__ __launch_bounds__(256)
void k_feat(const int* __restrict__ item_id, const int* __restrict__ likes,
            const int* __restrict__ views, const int* __restrict__ item_seq,
            const unsigned short* __restrict__ iembb, const float* __restrict__ cate_emb,
            unsigned short* __restrict__ xb)
{
  const int b = blockIdx.x * 4 + (threadIdx.x >> 6);
  const int lane = threadIdx.x & 63;
  const int g = lane >> 4, l16 = lane & 15;
  const size_t base = (size_t)b * 768;
  const int li = likes[b], vi = views[b], id = item_id[b];

  // group g: entries g, g+4, ..., (<50): 13 for g<2, 12 for g>=2 (pad 0)
  const int ng = (g < 2) ? 13 : 12;
  int idxs[13];
  #pragma unroll
  for (int e = 0; e < 13; e++)
    idxs[e] = (e < ng) ? item_seq[b * 50 + g + 4 * e] : 0;

  float acc[8] = {0.f, 0.f, 0.f, 0.f, 0.f, 0.f, 0.f, 0.f};
  float cnt = 0.f;
  #pragma unroll
  for (int e = 0; e < 13; e++) {
    const int idx = idxs[e];
    if (idx != 0) {
      cnt += 1.0f;
      uint4 v = *(const uint4*)&iembb[(size_t)idx * 128 + l16 * 8];
      const unsigned int u0 = v.x, u1 = v.y, u2 = v.z, u3 = v.w;
      acc[0] += bf2f((unsigned short)(u0 & 0xFFFFu));
      acc[1] += bf2f((unsigned short)(u0 >> 16));
      acc[2] += bf2f((unsigned short)(u1 & 0xFFFFu));
      acc[3] += bf2f((unsigned short)(u1 >> 16));
      acc[4] += bf2f((unsigned short)(u2 & 0xFFFFu));
      acc[5] += bf2f((unsigned short)(u2 >> 16));
      acc[6] += bf2f((unsigned short)(u3 & 0xFFFFu));
      acc[7] += bf2f((unsigned short)(u3 >> 16));
    }
  }
  // reduce the 4 groups (same l16 slice, disjoint entry sets)
  #pragma unroll
  for (int k = 0; k < 8; k++) {
    acc[k] += __shfl_xor(acc[k], 16, 64);
    acc[k] += __shfl_xor(acc[k], 32, 64);
  }
  cnt += __shfl_xor(cnt, 16, 64);
  cnt += __shfl_xor(cnt, 32, 64);
  const float ic = 1.0f / fmaxf(cnt, 1.0f);

  *(unsigned int*)&xb[base + lane * 2] = 0u;            // row 0 zeros (all lanes)

  if (g == 0) {                                         // row 5: hist mean
    uint4 o;
    o.x = (unsigned int)f2bf(acc[0] * ic) | ((unsigned int)f2bf(acc[1] * ic) << 16);
    o.y = (unsigned int)f2bf(acc[2] * ic) | ((unsigned int)f2bf(acc[3] * ic) << 16);
    o.z = (unsigned int)f2bf(acc[4] * ic) | ((unsigned int)f2bf(acc[5] * ic) << 16);
    o.w = (unsigned int)f2bf(acc[6] * ic) | ((unsigned int)f2bf(acc[7] * ic) << 16);
    *(uint4*)&xb[base + 640 + l16 * 8] = o;
  } else if (g == 1) {                                  // row 3: id (bf16 copy)
    *(uint4*)&xb[base + 384 + l16 * 8] =
        *(const uint4*)&iembb[(size_t)id * 128 + l16 * 8];
  } else {                                              // rows 1/2: like/view
    const int ci = (g == 2) ? li : vi;
    const float4 v0 = *(const float4*)&cate_emb[(size_t)ci * 128 + l16 * 8];
    const float4 v1 = *(const float4*)&cate_emb[(size_t)ci * 128 + l16 * 8 + 4];
    uint4 o;
    o.x = (unsigned int)f2bf(v0.x) | ((unsigned int)f2bf(v0.y) << 16);
    o.y = (unsigned int)f2bf(v0.z) | ((unsigned int)f2bf(v0.w) << 16);
    o.z = (unsigned int)f2bf(v1.x) | ((unsigned int)f2bf(v1.y) << 16);
    o.w = (unsigned int)f2bf(v1.z) | ((unsigned int)f2bf(v1.w) << 16);
    *(uint4*)&xb[base + 128 + (g - 2) * 128 + l16 * 8] = o;
  }
}

// ---------------------------------------------------------------------------
// Fused MLP2 + bn+gelu + final 256-dot + sigmoid -> out
// ---------------------------------------------------------------------------
__global__ __launch_bounds__(512)
void k_mlp2out(const unsigned short* __restrict__ A, const unsigned short* __restrict__ Bt,
               const float* __restrict__ b2v, const float* __restrict__ bng,
               const float* __restrict__ bnb, const float* __restrict__ w3,
               const float* __restrict__ b3, float* __restrict__ out)
{
  __shared__ __align__(16) char smem[40960];
  unsigned short* As = (unsigned short*)smem;
  unsigned short* Bs = (unsigned short*)(smem + 8192);
  unsigned short* h2s = (unsigned short*)smem;

  const int t = threadIdx.x, lane = t & 63, w = t >> 6;
  const int lr = lane & 15, lq = lane >> 4;
  const int m0 = blockIdx.x * 64;

  floatx4 acc[4][2];
  #pragma unroll
  for (int a = 0; a < 4; a++)
    #pragma unroll
    for (int b = 0; b < 2; b++) acc[a][b] = (floatx4){0.f, 0.f, 0.f, 0.f};

  const int srow = lane >> 3;
  const int schk = (lane & 7) ^ srow;
  const int rb0 = w * 40;

  for (int k0 = 0; k0 < 512; k0 += 64) {
    __syncthreads();
    #pragma unroll
    for (int q = 0; q < 5; q++) {
      const int rb = rb0 + q * 8;
      if (rb < 64) ALOAD16(A + (size_t)(m0 + rb + srow) * 512 + k0 + schk * 8, As + rb * 64);
      else { const int rbb = rb - 64; ALOAD16(Bt + (size_t)(rbb + srow) * 512 + k0 + schk * 8, Bs + rbb * 64); }
    }
    __syncthreads();
    #pragma unroll
    for (int ko = 0; ko < 2; ko++) {
      bf16x8 af[4], bfv[2];
      #pragma unroll
      for (int mt = 0; mt < 4; mt++) {
        const int row = mt * 16 + lr;
        const int pc = (ko * 4 + lq) ^ (lr & 7);
        af[mt] = __builtin_bit_cast(bf16x8, *(const uint4*)&As[row * 64 + pc * 8]);
      }
      #pragma unroll
      for (int nt = 0; nt < 2; nt++) {
        const int row = w * 32 + nt * 16 + lr;
        const int pc = (ko * 4 + lq) ^ (lr & 7);
        bfv[nt] = __builtin_bit_cast(bf16x8, *(const uint4*)&Bs[row * 64 + pc * 8]);
      }
      #pragma unroll
      for (int mt = 0; mt < 4; mt++)
        #pragma unroll
        for (int nt = 0; nt < 2; nt++)
          acc[mt][nt] = __builtin_amdgcn_mfma_f32_16x16x32_bf16(af[mt], bfv[nt], acc[mt][nt], 0, 0, 0);
    }
  }

  __syncthreads();
  #pragma unroll
  for (int mt = 0; mt < 4; mt++)
    #pragma unroll
    for (int nt = 0; nt < 2; nt++)
      #pragma unroll
      for (int i = 0; i < 4; i++) {
        const int rr = mt * 16 + lq * 4 + i;
        const int cc = w * 32 + nt * 16 + lr;
        float tt = acc[mt][nt][i] + b2v[cc];
        tt = tt * (bng[cc] * 0.9999950000374997f) + bnb[cc];
        h2s[rr * 264 + cc] = f2bf(gelu_exact(tt));
      }
  __syncthreads();

  const float4 w4 = *(const float4*)&w3[lane * 4];
  #pragma unroll
  for (int rr = 0; rr < 8; rr++) {
    const int r = w * 8 + rr;
    ushort4 v = *(const ushort4*)&h2s[r * 264 + lane * 4];
    float a = bf2f(v.x) * w4.x + bf2f(v.y) * w4.y + bf2f(v.z) * w4.z + bf2f(v.w) * w4.w;
    #pragma unroll
    for (int o = 32; o > 0; o >>= 1) a += __shfl_xor(a, o, 64);
    if (lane == 0) out[m0 + r] = 1.0f / (1.0f + __expf(-(a + b3[0])));
  }
}

// ---------------------------------------------------------------------------
// Workspace layout (bytes).  Peak ~203 MB (+ wallt2 at tail).
// ---------------------------------------------------------------------------
#define OFF_MMWT   0ull           // 32768
#define OFF_BIWT   65536ull       // 163840
#define OFF_W1T    229376ull      // 2752512
#define OFF_W2T    2981888ull     // 262144
#define OFF_IMMB   3244032ull     // 4194304
#define OFF_XB     7438336ull     // 25165824  (alias: h1 later)
#define OFF_SB     57769984ull    // 25165824
#define OFF_C      82935808ull    // 88080384
#define OFF_IEMB   179404800ull   // 23479808
#define OFF_WALLT2 202884608ull   // 36864 -> total 202921472

extern "C" void kernel_launch(void* const* d_in, const int* in_sizes, int n_in,
                              void* d_out, int out_size, void* d_ws, size_t ws_size,
                              hipStream_t stream)
{
  const int*   item_id  = (const int*)  d_in[0];
  const float* item_mm  = (const float*)d_in[1];
  const int*   likes    = (const int*)  d_in[2];
  const int*   views    = (const int*)  d_in[3];
  const int*   item_seq = (const int*)  d_in[4];
  const float* item_emb = (const float*)d_in[5];
  const float* cate_emb = (const float*)d_in[6];
  const float* mm_w     = (const float*)d_in[7];
  const float* mm_b     = (const float*)d_in[8];
  const float* ln_g     = (const float*)d_in[9];
  const float* ln_b     = (const float*)d_in[10];
  const float* gnn_W    = (const float*)d_in[11];
  const float* gnn_a    = (const float*)d_in[12];
  const float* se_w1    = (const float*)d_in[13];
  const float* se_b1    = (const float*)d_in[14];
  const float* se_w2    = (const float*)d_in[15];
  const float* se_b2    = (const float*)d_in[16];
  const float* bi_W     = (const float*)d_in[17];
  const float* mlp_w1   = (const float*)d_in[18];
  const float* mlp_b1   = (const float*)d_in[19];
  const float* bn1_g    = (const float*)d_in[20];
  const float* bn1_b    = (const float*)d_in[21];
  const float* mlp_w2   = (const float*)d_in[22];
  const float* mlp_b2   = (const float*)d_in[23];
  const float* bn2_g    = (const float*)d_in[24];
  const float* bn2_b    = (const float*)d_in[25];
  const float* mlp_w3   = (const float*)d_in[26];
  const float* mlp_b3   = (const float*)d_in[27];
  float* out = (float*)d_out;

  char* ws = (char*)d_ws;
  unsigned short* mmwt   = (unsigned short*)(ws + OFF_MMWT);
  unsigned short* biwt   = (unsigned short*)(ws + OFF_BIWT);
  unsigned short* w1t    = (unsigned short*)(ws + OFF_W1T);
  unsigned short* w2t    = (unsigned short*)(ws + OFF_W2T);
  unsigned short* immb   = (unsigned short*)(ws + OFF_IMMB);
  unsigned short* xb     = (unsigned short*)(ws + OFF_XB);
  unsigned short* sbb    = (unsigned short*)(ws + OFF_SB);
  unsigned short* cbuf   = (unsigned short*)(ws + OFF_C);
  unsigned short* h1b    = (unsigned short*)(ws + OFF_XB);   // alias: xb dead after k_hpatt
  unsigned short* iembb  = (unsigned short*)(ws + OFF_IEMB);
  unsigned short* wallt2 = (unsigned short*)(ws + OFF_WALLT2);

  // 1. packs (wallt2 with fused ei/ej cols + item_mm/item_emb vec4 converts)
  k_pack<<<4096, 256, 0, stream>>>(gnn_W, gnn_a, item_mm, item_emb, wallt2, immb, iembb);
  // 2. merged LDS-tiled transposes: w1, w2, bi_W, mm_w
  k_transp2<<<392, 256, 0, stream>>>(mlp_w1, mlp_w2, bi_W, mm_w, w1t, w2t, biwt, mmwt);
  // 3. feature rows 0,1,2,3,5 (16 B/lane gathers, quarter-wave groups)
  k_feat<<<BB / 4, 256, 0, stream>>>(item_id, likes, views, item_seq, iembb, cate_emb, xb);
  // 4. fused mm GEMM + bias + LN + GELU -> xb row 4
  k_mmln<<<256, 512, 0, stream>>>(immb, mmwt, mm_b, ln_g, ln_b, xb);
  // 5. fused hp GEMM (ei/ej in-GEMM) + attention + SE -> c[:, :768], sb
  k_hpatt<<<1024, 256, 0, stream>>>(xb, wallt2, se_w1, se_b1, se_w2, se_b2, cbuf, sbb);
  // 6. vid GEMM + pairs -> c[:, 768:]
  gemm_vid<<<dim3(1, 128, 5), 256, 0, stream>>>(sbb, biwt, cbuf);
  // 7. MLP1: h1 = gelu(bn1(c @ w1 + b1)), BK=64 (0-conflict layout)
  gemm_mlp1<<<dim3(4, 128), 512, 0, stream>>>(cbuf, w1t, h1b, mlp_b1, bn1_g, bn1_b);
  // 8. fused MLP2 + bn + gelu + dot(w3) + sigmoid -> out
  k_mlp2out<<<256, 512, 0, stream>>>(h1b, w2t, mlp_b2, bn2_g, bn2_b, mlp_w3, mlp_b3, out);
}

// Round 14
// 329.722 us; speedup vs baseline: 1.0512x; 1.0109x over previous
//
#include <hip/hip_runtime.h>
#include <hip/hip_bf16.h>
#include <cstdint>
#include <cstddef>

#define BB 16384

typedef float  floatx4 __attribute__((ext_vector_type(4)));
typedef __bf16 bf16x8  __attribute__((ext_vector_type(8)));

__device__ __forceinline__ unsigned short f2bf(float f) {
  union { float f; unsigned int u; } v; v.f = f;
  unsigned int r = v.u + 0x7FFFu + ((v.u >> 16) & 1u);
  return (unsigned short)(r >> 16);
}
__device__ __forceinline__ float bf2f(unsigned short h) {
  union { unsigned int u; float f; } v; v.u = ((unsigned int)h) << 16;
  return v.f;
}
__device__ __forceinline__ float gelu_exact(float x) {
  return 0.5f * x * (1.0f + erff(x * 0.7071067811865475f));
}

// async global->LDS, 16B per lane; LDS dest = wave-uniform base + lane*16
#define ALOAD16(g, l) \
  __builtin_amdgcn_global_load_lds((const __attribute__((address_space(1))) void*)(g), \
                                   (__attribute__((address_space(3))) void*)(l), 16, 0, 0)

// ---------------------------------------------------------------------------
// k_prep: MERGED pack + transposes (independent read/write sets).
//   blocks 0..2047   : grid-stride pack jobs
//     [wallt2 18432 scalar | immb 524288 vec4 | iembb 2934976 vec4]
//     boundaries: 18432 / 542720 / 3477696   (R13 bug: immb was 131072)
//   blocks 2048..2439: LDS-tiled transposes (w1, w2, bi_W, mm_w)
// ---------------------------------------------------------------------------
__global__ __launch_bounds__(256)
void k_prep(const float* __restrict__ gnn_W, const float* __restrict__ gnn_a,
            const float* __restrict__ item_mm, const float* __restrict__ item_emb,
            const float* __restrict__ w1, const float* __restrict__ w2,
            const float* __restrict__ bi_W, const float* __restrict__ mm_w,
            unsigned short* __restrict__ wallt2, unsigned short* __restrict__ immb,
            unsigned short* __restrict__ iembb,
            unsigned short* __restrict__ w1t, unsigned short* __restrict__ w2t,
            unsigned short* __restrict__ biwt, unsigned short* __restrict__ mmwt)
{
  __shared__ float tile[64][65];
  if (blockIdx.x < 2048) {
    const int total = 18432 + 524288 + 2934976;   // 3477696 jobs
    for (int id = blockIdx.x * 256 + threadIdx.x; id < total; id += 2048 * 256) {
      if (id < 18432) {                  // wallt2[n][k], n < 144
        int n = id / 128, k = id % 128;
        if (n < 128) {
          wallt2[id] = f2bf(gnn_W[(n >> 5) * 4096 + k * 32 + (n & 31)]);
        } else if (n < 136) {            // q1 (128..131) / q2 (132..135)
          int h = (n - 128) & 3;
          int off = (n < 132) ? 0 : 32;
          float s = 0.f;
          for (int o = 0; o < 32; o++)
            s += gnn_W[h * 4096 + k * 32 + o] * gnn_a[h * 64 + off + o];
          wallt2[id] = f2bf(s);
        } else {
          wallt2[id] = 0;
        }
      } else if (id < 542720) {          // immb cvt vec4 (524288 jobs)
        int l = id - 18432;
        float4 v = ((const float4*)item_mm)[l];
        ushort4 o; o.x = f2bf(v.x); o.y = f2bf(v.y); o.z = f2bf(v.z); o.w = f2bf(v.w);
        ((ushort4*)immb)[l] = o;
      } else {                           // iembb cvt vec4 (2934976 jobs)
        int l = id - 542720;
        float4 v = ((const float4*)item_emb)[l];
        ushort4 o; o.x = f2bf(v.x); o.y = f2bf(v.y); o.z = f2bf(v.z); o.w = f2bf(v.w);
        ((ushort4*)iembb)[l] = o;
      }
    }
  } else {
    int blk = blockIdx.x - 2048;
    const float* in; unsigned short* outp; int R, C, bx, by;
    if (blk < 336)      { in = w1; outp = w1t; R = 2688; C = 512; bx = blk % 8; by = blk / 8; }
    else if (blk < 368) { blk -= 336; in = w2; outp = w2t; R = 512; C = 256; bx = blk % 4; by = blk / 4; }
    else if (blk < 388) { blk -= 368; int f = blk / 4; int r2 = blk % 4;
                          in = bi_W + f * 16384; outp = biwt + f * 16384;
                          R = 128; C = 128; bx = r2 % 2; by = r2 / 2; }
    else                { blk -= 388; in = mm_w; outp = mmwt; R = 128; C = 128;
                          bx = blk % 2; by = blk / 2; }
    const int c0 = bx * 64, r0 = by * 64;
    const int lr = threadIdx.x >> 6;
    const int lc = threadIdx.x & 63;
    #pragma unroll
    for (int i = 0; i < 16; i++) {
      int r = lr + i * 4;
      tile[r][lc] = in[(size_t)(r0 + r) * C + c0 + lc];
    }
    __syncthreads();
    #pragma unroll
    for (int i = 0; i < 16; i++) {
      int c = lr + i * 4;
      outp[(size_t)(c0 + c) * R + r0 + lc] = f2bf(tile[lc][c]);
    }
  }
}

// ---------------------------------------------------------------------------
// k_featmm: MERGED feature build + mm GEMM/LN/GELU (disjoint xb rows).
//   blocks 0..2047   : feat — 8 batches/block (one wave each); quarter-wave
//                      16 B/lane gathers
//   blocks 2048..2303: mmln — y = item_mm @ mm_w + b -> LN -> GELU -> xb row 4
// ---------------------------------------------------------------------------
__global__ __launch_bounds__(512)
void k_featmm(const int* __restrict__ item_id, const int* __restrict__ likes,
              const int* __restrict__ views, const int* __restrict__ item_seq,
              const unsigned short* __restrict__ iembb, const float* __restrict__ cate_emb,
              const unsigned short* __restrict__ immb, const unsigned short* __restrict__ mmwt,
              const float* __restrict__ mm_b, const float* __restrict__ ln_g,
              const float* __restrict__ ln_b, unsigned short* __restrict__ xb)
{
  __shared__ __align__(16) char smem[64 * 130 * 4];    // mmln only
  const int t = threadIdx.x, lane = t & 63, w = t >> 6;

  if (blockIdx.x < 2048) {
    // ------------------ feat: one wave per batch row ------------------
    const int b = blockIdx.x * 8 + w;
    const int g = lane >> 4, l16 = lane & 15;
    const size_t base = (size_t)b * 768;
    const int li = likes[b], vi = views[b], id = item_id[b];

    const int ng = (g < 2) ? 13 : 12;
    int idxs[13];
    #pragma unroll
    for (int e = 0; e < 13; e++)
      idxs[e] = (e < ng) ? item_seq[b * 50 + g + 4 * e] : 0;

    float acc[8] = {0.f, 0.f, 0.f, 0.f, 0.f, 0.f, 0.f, 0.f};
    float cnt = 0.f;
    #pragma unroll
    for (int e = 0; e < 13; e++) {
      const int idx = idxs[e];
      if (idx != 0) {
        cnt += 1.0f;
        uint4 v = *(const uint4*)&iembb[(size_t)idx * 128 + l16 * 8];
        acc[0] += bf2f((unsigned short)(v.x & 0xFFFFu));
        acc[1] += bf2f((unsigned short)(v.x >> 16));
        acc[2] += bf2f((unsigned short)(v.y & 0xFFFFu));
        acc[3] += bf2f((unsigned short)(v.y >> 16));
        acc[4] += bf2f((unsigned short)(v.z & 0xFFFFu));
        acc[5] += bf2f((unsigned short)(v.z >> 16));
        acc[6] += bf2f((unsigned short)(v.w & 0xFFFFu));
        acc[7] += bf2f((unsigned short)(v.w >> 16));
      }
    }
    #pragma unroll
    for (int k = 0; k < 8; k++) {
      acc[k] += __shfl_xor(acc[k], 16, 64);
      acc[k] += __shfl_xor(acc[k], 32, 64);
    }
    cnt += __shfl_xor(cnt, 16, 64);
    cnt += __shfl_xor(cnt, 32, 64);
    const float ic = 1.0f / fmaxf(cnt, 1.0f);

    *(unsigned int*)&xb[base + lane * 2] = 0u;          // row 0 zeros

    if (g == 0) {                                       // row 5: hist mean
      uint4 o;
      o.x = (unsigned int)f2bf(acc[0] * ic) | ((unsigned int)f2bf(acc[1] * ic) << 16);
      o.y = (unsigned int)f2bf(acc[2] * ic) | ((unsigned int)f2bf(acc[3] * ic) << 16);
      o.z = (unsigned int)f2bf(acc[4] * ic) | ((unsigned int)f2bf(acc[5] * ic) << 16);
      o.w = (unsigned int)f2bf(acc[6] * ic) | ((unsigned int)f2bf(acc[7] * ic) << 16);
      *(uint4*)&xb[base + 640 + l16 * 8] = o;
    } else if (g == 1) {                                // row 3: id copy
      *(uint4*)&xb[base + 384 + l16 * 8] =
          *(const uint4*)&iembb[(size_t)id * 128 + l16 * 8];
    } else {                                            // rows 1/2: like/view
      const int ci = (g == 2) ? li : vi;
      const float4 v0 = *(const float4*)&cate_emb[(size_t)ci * 128 + l16 * 8];
      const float4 v1 = *(const float4*)&cate_emb[(size_t)ci * 128 + l16 * 8 + 4];
      uint4 o;
      o.x = (unsigned int)f2bf(v0.x) | ((unsigned int)f2bf(v0.y) << 16);
      o.y = (unsigned int)f2bf(v0.z) | ((unsigned int)f2bf(v0.w) << 16);
      o.z = (unsigned int)f2bf(v1.x) | ((unsigned int)f2bf(v1.y) << 16);
      o.w = (unsigned int)f2bf(v1.z) | ((unsigned int)f2bf(v1.w) << 16);
      *(uint4*)&xb[base + 128 + (g - 2) * 128 + l16 * 8] = o;
    }
    return;
  }

  // ------------------ mmln: 64x128 GEMM + bias + LN + GELU ------------------
  unsigned short* As = (unsigned short*)smem;           // 64*64
  unsigned short* Bs = (unsigned short*)(smem + 8192);  // 128*64
  float* cls = (float*)smem;                            // 64*130 after barrier

  const int lr = lane & 15, lq = lane >> 4;
  const int m0 = (blockIdx.x - 2048) * 64;

  floatx4 acc[4];
  #pragma unroll
  for (int a = 0; a < 4; a++) acc[a] = (floatx4){0.f, 0.f, 0.f, 0.f};

  const int srow = lane >> 3;
  const int schk = (lane & 7) ^ srow;
  const int rb0 = w * 24;

  for (int k0 = 0; k0 < 128; k0 += 64) {
    __syncthreads();
    #pragma unroll
    for (int q = 0; q < 3; q++) {
      const int rb = rb0 + q * 8;
      if (rb < 64) ALOAD16(immb + (size_t)(m0 + rb + srow) * 128 + k0 + schk * 8, As + rb * 64);
      else { const int rbb = rb - 64; ALOAD16(mmwt + (size_t)(rbb + srow) * 128 + k0 + schk * 8, Bs + rbb * 64); }
    }
    __syncthreads();
    #pragma unroll
    for (int ko = 0; ko < 2; ko++) {
      bf16x8 af[4], bv;
      #pragma unroll
      for (int mt = 0; mt < 4; mt++) {
        const int row = mt * 16 + lr;
        const int pc = (ko * 4 + lq) ^ (lr & 7);
        af[mt] = __builtin_bit_cast(bf16x8, *(const uint4*)&As[row * 64 + pc * 8]);
      }
      {
        const int row = w * 16 + lr;
        const int pc = (ko * 4 + lq) ^ (lr & 7);
        bv = __builtin_bit_cast(bf16x8, *(const uint4*)&Bs[row * 64 + pc * 8]);
      }
      #pragma unroll
      for (int mt = 0; mt < 4; mt++)
        acc[mt] = __builtin_amdgcn_mfma_f32_16x16x32_bf16(af[mt], bv, acc[mt], 0, 0, 0);
    }
  }

  __syncthreads();
  #pragma unroll
  for (int mt = 0; mt < 4; mt++)
    #pragma unroll
    for (int i = 0; i < 4; i++) {
      const int rr = mt * 16 + lq * 4 + i;
      const int cc = w * 16 + lr;
      cls[rr * 130 + cc] = acc[mt][i] + mm_b[cc];
    }
  __syncthreads();

  const float2 g2 = *(const float2*)&ln_g[lane * 2];
  const float2 b2 = *(const float2*)&ln_b[lane * 2];
  #pragma unroll
  for (int rr = 0; rr < 8; rr++) {
    const int r = w * 8 + rr;
    float2 v = *(const float2*)&cls[r * 130 + lane * 2];
    float s = v.x + v.y, s2 = v.x * v.x + v.y * v.y;
    #pragma unroll
    for (int o = 32; o > 0; o >>= 1) { s += __shfl_xor(s, o, 64); s2 += __shfl_xor(s2, o, 64); }
    float mu  = s * (1.0f / 128.0f);
    float var = s2 * (1.0f / 128.0f) - mu * mu;
    float rs  = rsqrtf(var + 1e-5f);
    float t0 = gelu_exact((v.x - mu) * rs * g2.x + b2.x);
    float t1 = gelu_exact((v.y - mu) * rs * g2.y + b2.y);
    unsigned int pk = (unsigned int)f2bf(t0) | ((unsigned int)f2bf(t1) << 16);
    *(unsigned int*)&xb[(size_t)(m0 + r) * 768 + 512 + lane * 2] = pk;
  }
}

// ---------------------------------------------------------------------------
// MLP1 GEMM: h1 = gelu(bn1(c @ w1 + b1)).  128x128 tile, BK=64, 512 thr,
// 8 waves 2x4.  XOR-8 swizzled global_load_lds staging (0-conflict layout).
// ---------------------------------------------------------------------------
__global__ __launch_bounds__(512)
void gemm_mlp1(const unsigned short* __restrict__ A, const unsigned short* __restrict__ Bt,
               unsigned short* __restrict__ Cp,
               const float* __restrict__ bias, const float* __restrict__ bng,
               const float* __restrict__ bnb)
{
  int p = blockIdx.y * gridDim.x + blockIdx.x;
  int xcd = p & 7, slot = p >> 3;
  const int bx = slot % gridDim.x;
  const int by = xcd * (gridDim.y >> 3) + slot / gridDim.x;
  const int n0 = bx * 128;
  const int m0 = by * 128;

  __shared__ __align__(16) unsigned short As[128 * 64];   // 16 KB
  __shared__ __align__(16) unsigned short Bs[128 * 64];   // 16 KB
  const int t = threadIdx.x, lane = t & 63, w = t >> 6;
  const int wm = w & 1, wn = w >> 1;          // 2 x 4
  const int lr = lane & 15, lq = lane >> 4;

  floatx4 acc[4][2];
  #pragma unroll
  for (int a = 0; a < 4; a++)
    #pragma unroll
    for (int b = 0; b < 2; b++) acc[a][b] = (floatx4){0.f, 0.f, 0.f, 0.f};

  const int srow = lane >> 3;
  const int schk = (lane & 7) ^ srow;
  const int rb0 = w * 32;

  for (int k0 = 0; k0 < 2688; k0 += 64) {
    __syncthreads();
    #pragma unroll
    for (int q = 0; q < 4; q++) {
      const int rb = rb0 + q * 8;
      if (rb < 128) {
        ALOAD16(A + (size_t)(m0 + rb + srow) * 2688 + k0 + schk * 8, As + rb * 64);
      } else {
        ALOAD16(Bt + (size_t)(n0 + rb - 128 + srow) * 2688 + k0 + schk * 8, Bs + (rb - 128) * 64);
      }
    }
    __syncthreads();
    #pragma unroll
    for (int ko = 0; ko < 2; ko++) {
      bf16x8 af[4], bfv[2];
      #pragma unroll
      for (int mt = 0; mt < 4; mt++) {
        const int row = wm * 64 + mt * 16 + lr;
        const int pc = (ko * 4 + lq) ^ (lr & 7);
        af[mt] = __builtin_bit_cast(bf16x8, *(const uint4*)&As[row * 64 + pc * 8]);
      }
      #pragma unroll
      for (int nt = 0; nt < 2; nt++) {
        const int row = wn * 32 + nt * 16 + lr;
        const int pc = (ko * 4 + lq) ^ (lr & 7);
        bfv[nt] = __builtin_bit_cast(bf16x8, *(const uint4*)&Bs[row * 64 + pc * 8]);
      }
      #pragma unroll
      for (int mt = 0; mt < 4; mt++)
        #pragma unroll
        for (int nt = 0; nt < 2; nt++)
          acc[mt][nt] = __builtin_amdgcn_mfma_f32_16x16x32_bf16(af[mt], bfv[nt], acc[mt][nt], 0, 0, 0);
    }
  }

  #pragma unroll
  for (int mt = 0; mt < 4; mt++)
    #pragma unroll
    for (int nt = 0; nt < 2; nt++)
      #pragma unroll
      for (int i = 0; i < 4; i++) {
        const int cm = m0 + wm * 64 + mt * 16 + lq * 4 + i;
        const int cn = n0 + wn * 32 + nt * 16 + lr;
        float tt = acc[mt][nt][i] + bias[cn];
        tt = tt * (bng[cn] * 0.9999950000374997f) + bnb[cn];
        Cp[(size_t)cm * 512 + cn] = f2bf(gelu_exact(tt));
      }
}

// ---------------------------------------------------------------------------
// Fused: hp GEMM (96x144x128, ei/ej as fused columns 128..135) -> GAT
// attention + ELU + SE -> c[:, :768], sb.  1024 blocks x 256 thr.
// Wave grid 2x2; 9 B-tiles covered by tid = wn + 2*nt (nt<5, nt<4 || wn==0).
// ---------------------------------------------------------------------------
__global__ __launch_bounds__(256)
void k_hpatt(const unsigned short* __restrict__ xb, const unsigned short* __restrict__ wallt2,
             const float* __restrict__ se_w1, const float* __restrict__ se_b1,
             const float* __restrict__ se_w2, const float* __restrict__ se_b2,
             unsigned short* __restrict__ c, unsigned short* __restrict__ sb)
{
  __shared__ __align__(16) char smem[30720];
  unsigned short* As = (unsigned short*)smem;            // 96*64  = 12288 B
  unsigned short* Bs = (unsigned short*)(smem + 12288);  // 144*64 = 18432 B
  unsigned short* hps = (unsigned short*)smem;           // 96*146 bf16 (alias)

  const int t = threadIdx.x, lane = t & 63, w = t >> 6;
  const int wm = w & 1, wn = w >> 1;                     // both in {0,1}
  const int lr = lane & 15, lq = lane >> 4;
  const int m0 = blockIdx.x * 96;

  floatx4 acc[3][5];
  #pragma unroll
  for (int a = 0; a < 3; a++)
    #pragma unroll
    for (int b = 0; b < 5; b++) acc[a][b] = (floatx4){0.f, 0.f, 0.f, 0.f};

  const int srow = lane >> 3;
  const int schk = (lane & 7) ^ srow;

  for (int k0 = 0; k0 < 128; k0 += 64) {
    __syncthreads();
    #pragma unroll
    for (int q = 0; q < 8; q++) {
      const int e = w + 4 * q;          // 30 issues: A rows 96 (12), B rows 144 (18)
      if (e < 30) {
        const int rb = e * 8;
        if (rb < 96) {
          ALOAD16(xb + (size_t)(m0 + rb + srow) * 128 + k0 + schk * 8, As + rb * 64);
        } else {
          const int rbb = rb - 96;
          ALOAD16(wallt2 + (size_t)(rbb + srow) * 128 + k0 + schk * 8, Bs + rbb * 64);
        }
      }
    }
    __syncthreads();
    #pragma unroll
    for (int ko = 0; ko < 2; ko++) {
      bf16x8 af[3];
      #pragma unroll
      for (int mt = 0; mt < 3; mt++) {
        const int row = wm * 48 + mt * 16 + lr;
        const int pc = (ko * 4 + lq) ^ (lr & 7);
        af[mt] = __builtin_bit_cast(bf16x8, *(const uint4*)&As[row * 64 + pc * 8]);
      }
      #pragma unroll
      for (int nt = 0; nt < 5; nt++) {
        if (nt < 4 || wn == 0) {
          const int tid = wn + 2 * nt;  // wn0: 0,2,4,6,8 ; wn1: 1,3,5,7
          const int row = tid * 16 + lr;
          const int pc = (ko * 4 + lq) ^ (lr & 7);
          bf16x8 bfv = __builtin_bit_cast(bf16x8, *(const uint4*)&Bs[row * 64 + pc * 8]);
          #pragma unroll
          for (int mt = 0; mt < 3; mt++)
            acc[mt][nt] = __builtin_amdgcn_mfma_f32_16x16x32_bf16(af[mt], bfv, acc[mt][nt], 0, 0, 0);
        }
      }
    }
  }

  __syncthreads();                     // staging dead; write bf16 hp tile (146 stride)
  #pragma unroll
  for (int mt = 0; mt < 3; mt++)
    #pragma unroll
    for (int nt = 0; nt < 5; nt++)
      if (nt < 4 || wn == 0) {
        const int tid = wn + 2 * nt;
        #pragma unroll
        for (int i = 0; i < 4; i++) {
          const int rr = wm * 48 + mt * 16 + lq * 4 + i;
          const int cc = tid * 16 + lr;
          hps[rr * 146 + cc] = f2bf(acc[mt][nt][i]);
        }
      }
  __syncthreads();

  const int hh = lane >> 4;            // head of col pair (2l, 2l+1)

  for (int it = 0; it < 4; it++) {
    const int lb = w * 4 + it;
    const int b = blockIdx.x * 16 + lb;
    const unsigned short* hb = hps + lb * 6 * 146;

    float2 vm[6];
    float ein[6], ejn[6];
    #pragma unroll
    for (int m = 0; m < 6; m++) {
      unsigned int pk = *(const unsigned int*)&hb[m * 146 + lane * 2];
      vm[m].x = bf2f((unsigned short)(pk & 0xFFFFu));
      vm[m].y = bf2f((unsigned short)(pk >> 16));
      ein[m] = bf2f(hb[m * 146 + 128 + hh]);
      ejn[m] = bf2f(hb[m * 146 + 132 + hh]);
    }

    float g0[6], g1[6], zz[6];
    #pragma unroll
    for (int n = 0; n < 6; n++) {
      float ev[6]; float mx = -1e30f;
      #pragma unroll
      for (int m = 0; m < 6; m++) {
        float e = ein[n] + ejn[m];
        e = e > 0.f ? e : 0.2f * e;
        ev[m] = e; mx = fmaxf(mx, e);
      }
      float ss = 0.f;
      #pragma unroll
      for (int m = 0; m < 6; m++) { ev[m] = __expf(ev[m] - mx); ss += ev[m]; }
      const float inv = 1.0f / ss;
      float hn0 = 0.f, hn1 = 0.f;
      #pragma unroll
      for (int m = 0; m < 6; m++) {
        const float a = ev[m] * inv;
        hn0 += a * vm[m].x; hn1 += a * vm[m].y;
      }
      unsigned int xp = *(const unsigned int*)&xb[(size_t)b * 768 + n * 128 + lane * 2];
      float A0 = hn0 + bf2f((unsigned short)(xp & 0xFFFFu));
      float A1 = hn1 + bf2f((unsigned short)(xp >> 16));
      A0 = A0 > 0.f ? A0 : __expf(A0) - 1.0f;     // ELU, fast exp
      A1 = A1 > 0.f ? A1 : __expf(A1) - 1.0f;
      g0[n] = A0; g1[n] = A1;
      float zacc = A0 + A1;
      #pragma unroll
      for (int o = 32; o > 0; o >>= 1) zacc += __shfl_xor(zacc, o, 64);
      zz[n] = zacc * (1.0f / 128.0f);
    }

    float rr3[3];
    #pragma unroll
    for (int j = 0; j < 3; j++) {
      float a = se_b1[j];
      #pragma unroll
      for (int n = 0; n < 6; n++) a += zz[n] * se_w1[n * 3 + j];
      rr3[j] = fmaxf(a, 0.f);
    }
    float wse[6];
    #pragma unroll
    for (int n = 0; n < 6; n++) {
      float a = se_b2[n];
      #pragma unroll
      for (int j = 0; j < 3; j++) a += rr3[j] * se_w2[j * 6 + n];
      wse[n] = 1.0f / (1.0f + __expf(-a));
    }

    #pragma unroll
    for (int n = 0; n < 6; n++) {
      unsigned int pc = (unsigned int)f2bf(g0[n]) | ((unsigned int)f2bf(g1[n]) << 16);
      unsigned int ps = (unsigned int)f2bf(g0[n] * wse[n]) | ((unsigned int)f2bf(g1[n] * wse[n]) << 16);
      *(unsigned int*)&c[(size_t)b * 2688 + n * 128 + lane * 2]  = pc;
      *(unsigned int*)&sb[(size_t)b * 768 + n * 128 + lane * 2]  = ps;
    }
  }
}

// ---------------------------------------------------------------------------
// vid GEMM + pairs, LDS-transposed epilogue
// ---------------------------------------------------------------------------
__global__ __launch_bounds__(256)
void gemm_vid(const unsigned short* __restrict__ sbb, const unsigned short* __restrict__ biwt,
              unsigned short* __restrict__ c)
{
  const int z = blockIdx.z;
  const int m0 = blockIdx.y * 128;
  __shared__ __align__(16) unsigned short smem[128 * 130];
  unsigned short* As = smem;
  unsigned short* Bs = smem + 8192;
  const int t = threadIdx.x;
  const int lane = t & 63, w = t >> 6;
  const int wm = w & 1, wn = w >> 1;
  const int lr = lane & 15, lq = lane >> 4;

  floatx4 acc[4][4];
  #pragma unroll
  for (int a = 0; a < 4; a++)
    #pragma unroll
    for (int b = 0; b < 4; b++) acc[a][b] = (floatx4){0.f, 0.f, 0.f, 0.f};

  const int srow = lane >> 3;
  const int schk = (lane & 7) ^ srow;
  const unsigned short* Ag = sbb + (size_t)(m0 + w * 32 + srow) * 768 + z * 128 + schk * 8;
  const unsigned short* Bg = biwt + z * 16384 + (size_t)(w * 32 + srow) * 128 + schk * 8;
  unsigned short* AsW = As + w * 32 * 64;
  unsigned short* BsW = Bs + w * 32 * 64;

  for (int k0 = 0; k0 < 128; k0 += 64) {
    __syncthreads();
    #pragma unroll
    for (int q = 0; q < 4; q++) {
      ALOAD16(Ag + k0 + (size_t)(q * 8) * 768, AsW + q * 512);
      ALOAD16(Bg + k0 + (size_t)(q * 8) * 128, BsW + q * 512);
    }
    __syncthreads();
    #pragma unroll
    for (int ko = 0; ko < 2; ko++) {
      bf16x8 af[4], bfv[4];
      #pragma unroll
      for (int mt = 0; mt < 4; mt++) {
        const int row = wm * 64 + mt * 16 + lr;
        const int pc = (ko * 4 + lq) ^ (lr & 7);
        af[mt] = __builtin_bit_cast(bf16x8, *(const uint4*)&As[row * 64 + pc * 8]);
      }
      #pragma unroll
      for (int nt = 0; nt < 4; nt++) {
        const int row = wn * 64 + nt * 16 + lr;
        const int pc = (ko * 4 + lq) ^ (lr & 7);
        bfv[nt] = __builtin_bit_cast(bf16x8, *(const uint4*)&Bs[row * 64 + pc * 8]);
      }
      #pragma unroll
      for (int mt = 0; mt < 4; mt++)
        #pragma unroll
        for (int nt = 0; nt < 4; nt++)
          acc[mt][nt] = __builtin_amdgcn_mfma_f32_16x16x32_bf16(af[mt], bfv[nt], acc[mt][nt], 0, 0, 0);
    }
  }

  __syncthreads();
  #pragma unroll
  for (int mt = 0; mt < 4; mt++)
    #pragma unroll
    for (int nt = 0; nt < 4; nt++)
      #pragma unroll
      for (int i = 0; i < 4; i++) {
        const int rr = wm * 64 + mt * 16 + lq * 4 + i;
        const int cc = wn * 64 + nt * 16 + lr;
        smem[rr * 130 + cc] = f2bf(acc[mt][nt][i]);
      }
  __syncthreads();

  const int pb0[5] = {0, 5, 9, 12, 14};
  const int npairs = 5 - z;
  const int tot = 128 * 32 * npairs;
  for (int e = t; e < tot; e += 256) {
    const int g  = e & 31;
    const int rp = e >> 5;
    const int p  = rp % npairs;
    const int r  = rp / npairs;
    ushort4 vv = *(const ushort4*)&smem[r * 130 + g * 4];
    ushort4 sv = *(const ushort4*)&sbb[(size_t)(m0 + r) * 768 + (z + 1 + p) * 128 + g * 4];
    ushort4 o;
    o.x = f2bf(bf2f(vv.x) * bf2f(sv.x));
    o.y = f2bf(bf2f(vv.y) * bf2f(sv.y));
    o.z = f2bf(bf2f(vv.z) * bf2f(sv.z));
    o.w = f2bf(bf2f(vv.w) * bf2f(sv.w));
    *(ushort4*)&c[(size_t)(m0 + r) * 2688 + 768 + (size_t)(pb0[z] + p) * 128 + g * 4] = o;
  }
}

// ---------------------------------------------------------------------------
// Fused MLP2 + bn+gelu + final 256-dot + sigmoid -> out
// ---------------------------------------------------------------------------
__global__ __launch_bounds__(512)
void k_mlp2out(const unsigned short* __restrict__ A, const unsigned short* __restrict__ Bt,
               const float* __restrict__ b2v, const float* __restrict__ bng,
               const float* __restrict__ bnb, const float* __restrict__ w3,
               const float* __restrict__ b3, float* __restrict__ out)
{
  __shared__ __align__(16) char smem[40960];
  unsigned short* As = (unsigned short*)smem;
  unsigned short* Bs = (unsigned short*)(smem + 8192);
  unsigned short* h2s = (unsigned short*)smem;

  const int t = threadIdx.x, lane = t & 63, w = t >> 6;
  const int lr = lane & 15, lq = lane >> 4;
  const int m0 = blockIdx.x * 64;

  floatx4 acc[4][2];
  #pragma unroll
  for (int a = 0; a < 4; a++)
    #pragma unroll
    for (int b = 0; b < 2; b++) acc[a][b] = (floatx4){0.f, 0.f, 0.f, 0.f};

  const int srow = lane >> 3;
  const int schk = (lane & 7) ^ srow;
  const int rb0 = w * 40;

  for (int k0 = 0; k0 < 512; k0 += 64) {
    __syncthreads();
    #pragma unroll
    for (int q = 0; q < 5; q++) {
      const int rb = rb0 + q * 8;
      if (rb < 64) ALOAD16(A + (size_t)(m0 + rb + srow) * 512 + k0 + schk * 8, As + rb * 64);
      else { const int rbb = rb - 64; ALOAD16(Bt + (size_t)(rbb + srow) * 512 + k0 + schk * 8, Bs + rbb * 64); }
    }
    __syncthreads();
    #pragma unroll
    for (int ko = 0; ko < 2; ko++) {
      bf16x8 af[4], bfv[2];
      #pragma unroll
      for (int mt = 0; mt < 4; mt++) {
        const int row = mt * 16 + lr;
        const int pc = (ko * 4 + lq) ^ (lr & 7);
        af[mt] = __builtin_bit_cast(bf16x8, *(const uint4*)&As[row * 64 + pc * 8]);
      }
      #pragma unroll
      for (int nt = 0; nt < 2; nt++) {
        const int row = w * 32 + nt * 16 + lr;
        const int pc = (ko * 4 + lq) ^ (lr & 7);
        bfv[nt] = __builtin_bit_cast(bf16x8, *(const uint4*)&Bs[row * 64 + pc * 8]);
      }
      #pragma unroll
      for (int mt = 0; mt < 4; mt++)
        #pragma unroll
        for (int nt = 0; nt < 2; nt++)
          acc[mt][nt] = __builtin_amdgcn_mfma_f32_16x16x32_bf16(af[mt], bfv[nt], acc[mt][nt], 0, 0, 0);
    }
  }

  __syncthreads();
  #pragma unroll
  for (int mt = 0; mt < 4; mt++)
    #pragma unroll
    for (int nt = 0; nt < 2; nt++)
      #pragma unroll
      for (int i = 0; i < 4; i++) {
        const int rr = mt * 16 + lq * 4 + i;
        const int cc = w * 32 + nt * 16 + lr;
        float tt = acc[mt][nt][i] + b2v[cc];
        tt = tt * (bng[cc] * 0.9999950000374997f) + bnb[cc];
        h2s[rr * 264 + cc] = f2bf(gelu_exact(tt));
      }
  __syncthreads();

  const float4 w4 = *(const float4*)&w3[lane * 4];
  #pragma unroll
  for (int rr = 0; rr < 8; rr++) {
    const int r = w * 8 + rr;
    ushort4 v = *(const ushort4*)&h2s[r * 264 + lane * 4];
    float a = bf2f(v.x) * w4.x + bf2f(v.y) * w4.y + bf2f(v.z) * w4.z + bf2f(v.w) * w4.w;
    #pragma unroll
    for (int o = 32; o > 0; o >>= 1) a += __shfl_xor(a, o, 64);
    if (lane == 0) out[m0 + r] = 1.0f / (1.0f + __expf(-(a + b3[0])));
  }
}

// ---------------------------------------------------------------------------
// Workspace layout (bytes).  Peak ~203 MB (+ wallt2 at tail).
// ---------------------------------------------------------------------------
#define OFF_MMWT   0ull           // 32768
#define OFF_BIWT   65536ull       // 163840
#define OFF_W1T    229376ull      // 2752512
#define OFF_W2T    2981888ull     // 262144
#define OFF_IMMB   3244032ull     // 4194304
#define OFF_XB     7438336ull     // 25165824  (alias: h1 later)
#define OFF_SB     57769984ull    // 25165824
#define OFF_C      82935808ull    // 88080384
#define OFF_IEMB   179404800ull   // 23479808
#define OFF_WALLT2 202884608ull   // 36864 -> total 202921472

extern "C" void kernel_launch(void* const* d_in, const int* in_sizes, int n_in,
                              void* d_out, int out_size, void* d_ws, size_t ws_size,
                              hipStream_t stream)
{
  const int*   item_id  = (const int*)  d_in[0];
  const float* item_mm  = (const float*)d_in[1];
  const int*   likes    = (const int*)  d_in[2];
  const int*   views    = (const int*)  d_in[3];
  const int*   item_seq = (const int*)  d_in[4];
  const float* item_emb = (const float*)d_in[5];
  const float* cate_emb = (const float*)d_in[6];
  const float* mm_w     = (const float*)d_in[7];
  const float* mm_b     = (const float*)d_in[8];
  const float* ln_g     = (const float*)d_in[9];
  const float* ln_b     = (const float*)d_in[10];
  const float* gnn_W    = (const float*)d_in[11];
  const float* gnn_a    = (const float*)d_in[12];
  const float* se_w1    = (const float*)d_in[13];
  const float* se_b1    = (const float*)d_in[14];
  const float* se_w2    = (const float*)d_in[15];
  const float* se_b2    = (const float*)d_in[16];
  const float* bi_W     = (const float*)d_in[17];
  const float* mlp_w1   = (const float*)d_in[18];
  const float* mlp_b1   = (const float*)d_in[19];
  const float* bn1_g    = (const float*)d_in[20];
  const float* bn1_b    = (const float*)d_in[21];
  const float* mlp_w2   = (const float*)d_in[22];
  const float* mlp_b2   = (const float*)d_in[23];
  const float* bn2_g    = (const float*)d_in[24];
  const float* bn2_b    = (const float*)d_in[25];
  const float* mlp_w3   = (const float*)d_in[26];
  const float* mlp_b3   = (const float*)d_in[27];
  float* out = (float*)d_out;

  char* ws = (char*)d_ws;
  unsigned short* mmwt   = (unsigned short*)(ws + OFF_MMWT);
  unsigned short* biwt   = (unsigned short*)(ws + OFF_BIWT);
  unsigned short* w1t    = (unsigned short*)(ws + OFF_W1T);
  unsigned short* w2t    = (unsigned short*)(ws + OFF_W2T);
  unsigned short* immb   = (unsigned short*)(ws + OFF_IMMB);
  unsigned short* xb     = (unsigned short*)(ws + OFF_XB);
  unsigned short* sbb    = (unsigned short*)(ws + OFF_SB);
  unsigned short* cbuf   = (unsigned short*)(ws + OFF_C);
  unsigned short* h1b    = (unsigned short*)(ws + OFF_XB);   // alias: xb dead after k_hpatt
  unsigned short* iembb  = (unsigned short*)(ws + OFF_IEMB);
  unsigned short* wallt2 = (unsigned short*)(ws + OFF_WALLT2);

  // 1. merged packs + transposes (independent jobs, one launch)
  k_prep<<<2440, 256, 0, stream>>>(gnn_W, gnn_a, item_mm, item_emb,
                                   mlp_w1, mlp_w2, bi_W, mm_w,
                                   wallt2, immb, iembb, w1t, w2t, biwt, mmwt);
  // 2. merged feature build + mm GEMM/LN/GELU (disjoint xb rows)
  k_featmm<<<2304, 512, 0, stream>>>(item_id, likes, views, item_seq, iembb, cate_emb,
                                     immb, mmwt, mm_b, ln_g, ln_b, xb);
  // 3. fused hp GEMM (ei/ej in-GEMM) + attention + SE -> c[:, :768], sb
  k_hpatt<<<1024, 256, 0, stream>>>(xb, wallt2, se_w1, se_b1, se_w2, se_b2, cbuf, sbb);
  // 4. vid GEMM + pairs -> c[:, 768:]
  gemm_vid<<<dim3(1, 128, 5), 256, 0, stream>>>(sbb, biwt, cbuf);
  // 5. MLP1: h1 = gelu(bn1(c @ w1 + b1)), BK=64 (0-conflict layout)
  gemm_mlp1<<<dim3(4, 128), 512, 0, stream>>>(cbuf, w1t, h1b, mlp_b1, bn1_g, bn1_b);
  // 6. fused MLP2 + bn + gelu + dot(w3) + sigmoid -> out
  k_mlp2out<<<256, 512, 0, stream>>>(h1b, w2t, mlp_b2, bn2_g, bn2_b, mlp_w3, mlp_b3, out);
}

// Round 15
// 317.405 us; speedup vs baseline: 1.0920x; 1.0388x over previous
//
#include <hip/hip_runtime.h>
#include <hip/hip_bf16.h>
#include <cstdint>
#include <cstddef>

#define BB 16384

typedef float  floatx4 __attribute__((ext_vector_type(4)));
typedef float  floatx2 __attribute__((ext_vector_type(2)));
typedef __bf16 bf16x8  __attribute__((ext_vector_type(8)));

__device__ __forceinline__ unsigned short f2bf(float f) {
  union { float f; unsigned int u; } v; v.f = f;
  unsigned int r = v.u + 0x7FFFu + ((v.u >> 16) & 1u);
  return (unsigned short)(r >> 16);
}
__device__ __forceinline__ float bf2f(unsigned short h) {
  union { unsigned int u; float f; } v; v.u = ((unsigned int)h) << 16;
  return v.f;
}
__device__ __forceinline__ float gelu_exact(float x) {
  return 0.5f * x * (1.0f + erff(x * 0.7071067811865475f));
}
// decode 8 fp8-e4m3 (packed in uint2) -> 8 floats via HW cvt
__device__ __forceinline__ void fp8x8_to_f32(uint2 v, float* o) {
  floatx2 p0 = __builtin_amdgcn_cvt_pk_f32_fp8((int)v.x, false);
  floatx2 p1 = __builtin_amdgcn_cvt_pk_f32_fp8((int)v.x, true);
  floatx2 p2 = __builtin_amdgcn_cvt_pk_f32_fp8((int)v.y, false);
  floatx2 p3 = __builtin_amdgcn_cvt_pk_f32_fp8((int)v.y, true);
  o[0] = p0.x; o[1] = p0.y; o[2] = p1.x; o[3] = p1.y;
  o[4] = p2.x; o[5] = p2.y; o[6] = p3.x; o[7] = p3.y;
}

// async global->LDS, 16B per lane; LDS dest = wave-uniform base + lane*16
#define ALOAD16(g, l) \
  __builtin_amdgcn_global_load_lds((const __attribute__((address_space(1))) void*)(g), \
                                   (__attribute__((address_space(3))) void*)(l), 16, 0, 0)

// ---------------------------------------------------------------------------
// k_prep: MERGED pack + transposes.
//   blocks 0..2047   : grid-stride pack jobs
//     [wallt2 18432 scalar | immb 524288 vec4 | iembf8 1467488 8-float jobs]
//     boundaries: 18432 / 542720 / 2010208
//   blocks 2048..2439: LDS-tiled transposes (w1, w2, bi_W, mm_w)
// ---------------------------------------------------------------------------
__global__ __launch_bounds__(256)
void k_prep(const float* __restrict__ gnn_W, const float* __restrict__ gnn_a,
            const float* __restrict__ item_mm, const float* __restrict__ item_emb,
            const float* __restrict__ w1, const float* __restrict__ w2,
            const float* __restrict__ bi_W, const float* __restrict__ mm_w,
            unsigned short* __restrict__ wallt2, unsigned short* __restrict__ immb,
            unsigned char* __restrict__ iembf8,
            unsigned short* __restrict__ w1t, unsigned short* __restrict__ w2t,
            unsigned short* __restrict__ biwt, unsigned short* __restrict__ mmwt)
{
  __shared__ float tile[64][65];
  if (blockIdx.x < 2048) {
    const int total = 18432 + 524288 + 1467488;   // 2010208 jobs
    for (int id = blockIdx.x * 256 + threadIdx.x; id < total; id += 2048 * 256) {
      if (id < 18432) {                  // wallt2[n][k], n < 144
        int n = id / 128, k = id % 128;
        if (n < 128) {
          wallt2[id] = f2bf(gnn_W[(n >> 5) * 4096 + k * 32 + (n & 31)]);
        } else if (n < 136) {            // q1 (128..131) / q2 (132..135)
          int h = (n - 128) & 3;
          int off = (n < 132) ? 0 : 32;
          float s = 0.f;
          for (int o = 0; o < 32; o++)
            s += gnn_W[h * 4096 + k * 32 + o] * gnn_a[h * 64 + off + o];
          wallt2[id] = f2bf(s);
        } else {
          wallt2[id] = 0;
        }
      } else if (id < 542720) {          // immb cvt vec4 (524288 jobs)
        int l = id - 18432;
        float4 v = ((const float4*)item_mm)[l];
        ushort4 o; o.x = f2bf(v.x); o.y = f2bf(v.y); o.z = f2bf(v.z); o.w = f2bf(v.w);
        ((ushort4*)immb)[l] = o;
      } else {                           // iembf8 encode, 8 floats/job (1467488)
        int l = id - 542720;
        const float4 v0 = ((const float4*)item_emb)[l * 2];
        const float4 v1 = ((const float4*)item_emb)[l * 2 + 1];
        int lo = __builtin_amdgcn_cvt_pk_fp8_f32(v0.x, v0.y, 0, false);
        lo     = __builtin_amdgcn_cvt_pk_fp8_f32(v0.z, v0.w, lo, true);
        int hi = __builtin_amdgcn_cvt_pk_fp8_f32(v1.x, v1.y, 0, false);
        hi     = __builtin_amdgcn_cvt_pk_fp8_f32(v1.z, v1.w, hi, true);
        uint2 o; o.x = (unsigned int)lo; o.y = (unsigned int)hi;
        ((uint2*)iembf8)[l] = o;
      }
    }
  } else {
    int blk = blockIdx.x - 2048;
    const float* in; unsigned short* outp; int R, C, bx, by;
    if (blk < 336)      { in = w1; outp = w1t; R = 2688; C = 512; bx = blk % 8; by = blk / 8; }
    else if (blk < 368) { blk -= 336; in = w2; outp = w2t; R = 512; C = 256; bx = blk % 4; by = blk / 4; }
    else if (blk < 388) { blk -= 368; int f = blk / 4; int r2 = blk % 4;
                          in = bi_W + f * 16384; outp = biwt + f * 16384;
                          R = 128; C = 128; bx = r2 % 2; by = r2 / 2; }
    else                { blk -= 388; in = mm_w; outp = mmwt; R = 128; C = 128;
                          bx = blk % 2; by = blk / 2; }
    const int c0 = bx * 64, r0 = by * 64;
    const int lr = threadIdx.x >> 6;
    const int lc = threadIdx.x & 63;
    #pragma unroll
    for (int i = 0; i < 16; i++) {
      int r = lr + i * 4;
      tile[r][lc] = in[(size_t)(r0 + r) * C + c0 + lc];
    }
    __syncthreads();
    #pragma unroll
    for (int i = 0; i < 16; i++) {
      int c = lr + i * 4;
      outp[(size_t)(c0 + c) * R + r0 + lc] = f2bf(tile[lc][c]);
    }
  }
}

// ---------------------------------------------------------------------------
// k_featmm: MERGED feature build + mm GEMM/LN/GELU (disjoint xb rows).
//   blocks 0..2047   : feat — 8 batches/block (one wave each); quarter-wave
//                      fp8 gathers (8 B/lane covers a 128 B row with 16 lanes)
//   blocks 2048..2303: mmln — y = item_mm @ mm_w + b -> LN -> GELU -> xb row 4
// ---------------------------------------------------------------------------
__global__ __launch_bounds__(512)
void k_featmm(const int* __restrict__ item_id, const int* __restrict__ likes,
              const int* __restrict__ views, const int* __restrict__ item_seq,
              const unsigned char* __restrict__ iembf8, const float* __restrict__ cate_emb,
              const unsigned short* __restrict__ immb, const unsigned short* __restrict__ mmwt,
              const float* __restrict__ mm_b, const float* __restrict__ ln_g,
              const float* __restrict__ ln_b, unsigned short* __restrict__ xb)
{
  __shared__ __align__(16) char smem[64 * 130 * 4];    // mmln only
  const int t = threadIdx.x, lane = t & 63, w = t >> 6;

  if (blockIdx.x < 2048) {
    // ------------------ feat: one wave per batch row ------------------
    const int b = blockIdx.x * 8 + w;
    const int g = lane >> 4, l16 = lane & 15;
    const size_t base = (size_t)b * 768;
    const int li = likes[b], vi = views[b], id = item_id[b];

    const int ng = (g < 2) ? 13 : 12;
    int idxs[13];
    #pragma unroll
    for (int e = 0; e < 13; e++)
      idxs[e] = (e < ng) ? item_seq[b * 50 + g + 4 * e] : 0;

    float acc[8] = {0.f, 0.f, 0.f, 0.f, 0.f, 0.f, 0.f, 0.f};
    float cnt = 0.f;
    #pragma unroll
    for (int e = 0; e < 13; e++) {
      const int idx = idxs[e];
      if (idx != 0) {
        cnt += 1.0f;
        uint2 v = *(const uint2*)&iembf8[(size_t)idx * 128 + l16 * 8];
        float dv[8];
        fp8x8_to_f32(v, dv);
        #pragma unroll
        for (int k = 0; k < 8; k++) acc[k] += dv[k];
      }
    }
    #pragma unroll
    for (int k = 0; k < 8; k++) {
      acc[k] += __shfl_xor(acc[k], 16, 64);
      acc[k] += __shfl_xor(acc[k], 32, 64);
    }
    cnt += __shfl_xor(cnt, 16, 64);
    cnt += __shfl_xor(cnt, 32, 64);
    const float ic = 1.0f / fmaxf(cnt, 1.0f);

    *(unsigned int*)&xb[base + lane * 2] = 0u;          // row 0 zeros

    if (g == 0) {                                       // row 5: hist mean
      uint4 o;
      o.x = (unsigned int)f2bf(acc[0] * ic) | ((unsigned int)f2bf(acc[1] * ic) << 16);
      o.y = (unsigned int)f2bf(acc[2] * ic) | ((unsigned int)f2bf(acc[3] * ic) << 16);
      o.z = (unsigned int)f2bf(acc[4] * ic) | ((unsigned int)f2bf(acc[5] * ic) << 16);
      o.w = (unsigned int)f2bf(acc[6] * ic) | ((unsigned int)f2bf(acc[7] * ic) << 16);
      *(uint4*)&xb[base + 640 + l16 * 8] = o;
    } else if (g == 1) {                                // row 3: id (fp8 -> bf16)
      uint2 v = *(const uint2*)&iembf8[(size_t)id * 128 + l16 * 8];
      float dv[8];
      fp8x8_to_f32(v, dv);
      uint4 o;
      o.x = (unsigned int)f2bf(dv[0]) | ((unsigned int)f2bf(dv[1]) << 16);
      o.y = (unsigned int)f2bf(dv[2]) | ((unsigned int)f2bf(dv[3]) << 16);
      o.z = (unsigned int)f2bf(dv[4]) | ((unsigned int)f2bf(dv[5]) << 16);
      o.w = (unsigned int)f2bf(dv[6]) | ((unsigned int)f2bf(dv[7]) << 16);
      *(uint4*)&xb[base + 384 + l16 * 8] = o;
    } else {                                            // rows 1/2: like/view
      const int ci = (g == 2) ? li : vi;
      const float4 v0 = *(const float4*)&cate_emb[(size_t)ci * 128 + l16 * 8];
      const float4 v1 = *(const float4*)&cate_emb[(size_t)ci * 128 + l16 * 8 + 4];
      uint4 o;
      o.x = (unsigned int)f2bf(v0.x) | ((unsigned int)f2bf(v0.y) << 16);
      o.y = (unsigned int)f2bf(v0.z) | ((unsigned int)f2bf(v0.w) << 16);
      o.z = (unsigned int)f2bf(v1.x) | ((unsigned int)f2bf(v1.y) << 16);
      o.w = (unsigned int)f2bf(v1.z) | ((unsigned int)f2bf(v1.w) << 16);
      *(uint4*)&xb[base + 128 + (g - 2) * 128 + l16 * 8] = o;
    }
    return;
  }

  // ------------------ mmln: 64x128 GEMM + bias + LN + GELU ------------------
  unsigned short* As = (unsigned short*)smem;           // 64*64
  unsigned short* Bs = (unsigned short*)(smem + 8192);  // 128*64
  float* cls = (float*)smem;                            // 64*130 after barrier

  const int lr = lane & 15, lq = lane >> 4;
  const int m0 = (blockIdx.x - 2048) * 64;

  floatx4 acc[4];
  #pragma unroll
  for (int a = 0; a < 4; a++) acc[a] = (floatx4){0.f, 0.f, 0.f, 0.f};

  const int srow = lane >> 3;
  const int schk = (lane & 7) ^ srow;
  const int rb0 = w * 24;

  for (int k0 = 0; k0 < 128; k0 += 64) {
    __syncthreads();
    #pragma unroll
    for (int q = 0; q < 3; q++) {
      const int rb = rb0 + q * 8;
      if (rb < 64) ALOAD16(immb + (size_t)(m0 + rb + srow) * 128 + k0 + schk * 8, As + rb * 64);
      else { const int rbb = rb - 64; ALOAD16(mmwt + (size_t)(rbb + srow) * 128 + k0 + schk * 8, Bs + rbb * 64); }
    }
    __syncthreads();
    #pragma unroll
    for (int ko = 0; ko < 2; ko++) {
      bf16x8 af[4], bv;
      #pragma unroll
      for (int mt = 0; mt < 4; mt++) {
        const int row = mt * 16 + lr;
        const int pc = (ko * 4 + lq) ^ (lr & 7);
        af[mt] = __builtin_bit_cast(bf16x8, *(const uint4*)&As[row * 64 + pc * 8]);
      }
      {
        const int row = w * 16 + lr;
        const int pc = (ko * 4 + lq) ^ (lr & 7);
        bv = __builtin_bit_cast(bf16x8, *(const uint4*)&Bs[row * 64 + pc * 8]);
      }
      #pragma unroll
      for (int mt = 0; mt < 4; mt++)
        acc[mt] = __builtin_amdgcn_mfma_f32_16x16x32_bf16(af[mt], bv, acc[mt], 0, 0, 0);
    }
  }

  __syncthreads();
  #pragma unroll
  for (int mt = 0; mt < 4; mt++)
    #pragma unroll
    for (int i = 0; i < 4; i++) {
      const int rr = mt * 16 + lq * 4 + i;
      const int cc = w * 16 + lr;
      cls[rr * 130 + cc] = acc[mt][i] + mm_b[cc];
    }
  __syncthreads();

  const float2 g2 = *(const float2*)&ln_g[lane * 2];
  const float2 b2 = *(const float2*)&ln_b[lane * 2];
  #pragma unroll
  for (int rr = 0; rr < 8; rr++) {
    const int r = w * 8 + rr;
    float2 v = *(const float2*)&cls[r * 130 + lane * 2];
    float s = v.x + v.y, s2 = v.x * v.x + v.y * v.y;
    #pragma unroll
    for (int o = 32; o > 0; o >>= 1) { s += __shfl_xor(s, o, 64); s2 += __shfl_xor(s2, o, 64); }
    float mu  = s * (1.0f / 128.0f);
    float var = s2 * (1.0f / 128.0f) - mu * mu;
    float rs  = rsqrtf(var + 1e-5f);
    float t0 = gelu_exact((v.x - mu) * rs * g2.x + b2.x);
    float t1 = gelu_exact((v.y - mu) * rs * g2.y + b2.y);
    unsigned int pk = (unsigned int)f2bf(t0) | ((unsigned int)f2bf(t1) << 16);
    *(unsigned int*)&xb[(size_t)(m0 + r) * 768 + 512 + lane * 2] = pk;
  }
}

// ---------------------------------------------------------------------------
// MLP1 GEMM: h1 = gelu(bn1(c @ w1 + b1)).  128x128 tile, BK=64, 512 thr,
// 8 waves 2x4.  XOR-8 swizzled global_load_lds staging (0-conflict layout).
// ---------------------------------------------------------------------------
__global__ __launch_bounds__(512)
void gemm_mlp1(const unsigned short* __restrict__ A, const unsigned short* __restrict__ Bt,
               unsigned short* __restrict__ Cp,
               const float* __restrict__ bias, const float* __restrict__ bng,
               const float* __restrict__ bnb)
{
  int p = blockIdx.y * gridDim.x + blockIdx.x;
  int xcd = p & 7, slot = p >> 3;
  const int bx = slot % gridDim.x;
  const int by = xcd * (gridDim.y >> 3) + slot / gridDim.x;
  const int n0 = bx * 128;
  const int m0 = by * 128;

  __shared__ __align__(16) unsigned short As[128 * 64];   // 16 KB
  __shared__ __align__(16) unsigned short Bs[128 * 64];   // 16 KB
  const int t = threadIdx.x, lane = t & 63, w = t >> 6;
  const int wm = w & 1, wn = w >> 1;          // 2 x 4
  const int lr = lane & 15, lq = lane >> 4;

  floatx4 acc[4][2];
  #pragma unroll
  for (int a = 0; a < 4; a++)
    #pragma unroll
    for (int b = 0; b < 2; b++) acc[a][b] = (floatx4){0.f, 0.f, 0.f, 0.f};

  const int srow = lane >> 3;
  const int schk = (lane & 7) ^ srow;
  const int rb0 = w * 32;

  for (int k0 = 0; k0 < 2688; k0 += 64) {
    __syncthreads();
    #pragma unroll
    for (int q = 0; q < 4; q++) {
      const int rb = rb0 + q * 8;
      if (rb < 128) {
        ALOAD16(A + (size_t)(m0 + rb + srow) * 2688 + k0 + schk * 8, As + rb * 64);
      } else {
        ALOAD16(Bt + (size_t)(n0 + rb - 128 + srow) * 2688 + k0 + schk * 8, Bs + (rb - 128) * 64);
      }
    }
    __syncthreads();
    #pragma unroll
    for (int ko = 0; ko < 2; ko++) {
      bf16x8 af[4], bfv[2];
      #pragma unroll
      for (int mt = 0; mt < 4; mt++) {
        const int row = wm * 64 + mt * 16 + lr;
        const int pc = (ko * 4 + lq) ^ (lr & 7);
        af[mt] = __builtin_bit_cast(bf16x8, *(const uint4*)&As[row * 64 + pc * 8]);
      }
      #pragma unroll
      for (int nt = 0; nt < 2; nt++) {
        const int row = wn * 32 + nt * 16 + lr;
        const int pc = (ko * 4 + lq) ^ (lr & 7);
        bfv[nt] = __builtin_bit_cast(bf16x8, *(const uint4*)&Bs[row * 64 + pc * 8]);
      }
      #pragma unroll
      for (int mt = 0; mt < 4; mt++)
        #pragma unroll
        for (int nt = 0; nt < 2; nt++)
          acc[mt][nt] = __builtin_amdgcn_mfma_f32_16x16x32_bf16(af[mt], bfv[nt], acc[mt][nt], 0, 0, 0);
    }
  }

  #pragma unroll
  for (int mt = 0; mt < 4; mt++)
    #pragma unroll
    for (int nt = 0; nt < 2; nt++)
      #pragma unroll
      for (int i = 0; i < 4; i++) {
        const int cm = m0 + wm * 64 + mt * 16 + lq * 4 + i;
        const int cn = n0 + wn * 32 + nt * 16 + lr;
        float tt = acc[mt][nt][i] + bias[cn];
        tt = tt * (bng[cn] * 0.9999950000374997f) + bnb[cn];
        Cp[(size_t)cm * 512 + cn] = f2bf(gelu_exact(tt));
      }
}

// ---------------------------------------------------------------------------
// Fused: hp GEMM (96x144x128, ei/ej as fused columns 128..135) -> GAT
// attention + ELU + SE -> c[:, :768], sb.  1024 blocks x 256 thr.
// Wave grid 2x2; 9 B-tiles covered by tid = wn + 2*nt (nt<5, nt<4 || wn==0).
// ---------------------------------------------------------------------------
__global__ __launch_bounds__(256)
void k_hpatt(const unsigned short* __restrict__ xb, const unsigned short* __restrict__ wallt2,
             const float* __restrict__ se_w1, const float* __restrict__ se_b1,
             const float* __restrict__ se_w2, const float* __restrict__ se_b2,
             unsigned short* __restrict__ c, unsigned short* __restrict__ sb)
{
  __shared__ __align__(16) char smem[30720];
  unsigned short* As = (unsigned short*)smem;            // 96*64  = 12288 B
  unsigned short* Bs = (unsigned short*)(smem + 12288);  // 144*64 = 18432 B
  unsigned short* hps = (unsigned short*)smem;           // 96*146 bf16 (alias)

  const int t = threadIdx.x, lane = t & 63, w = t >> 6;
  const int wm = w & 1, wn = w >> 1;                     // both in {0,1}
  const int lr = lane & 15, lq = lane >> 4;
  const int m0 = blockIdx.x * 96;

  floatx4 acc[3][5];
  #pragma unroll
  for (int a = 0; a < 3; a++)
    #pragma unroll
    for (int b = 0; b < 5; b++) acc[a][b] = (floatx4){0.f, 0.f, 0.f, 0.f};

  const int srow = lane >> 3;
  const int schk = (lane & 7) ^ srow;

  for (int k0 = 0; k0 < 128; k0 += 64) {
    __syncthreads();
    #pragma unroll
    for (int q = 0; q < 8; q++) {
      const int e = w + 4 * q;          // 30 issues: A rows 96 (12), B rows 144 (18)
      if (e < 30) {
        const int rb = e * 8;
        if (rb < 96) {
          ALOAD16(xb + (size_t)(m0 + rb + srow) * 128 + k0 + schk * 8, As + rb * 64);
        } else {
          const int rbb = rb - 96;
          ALOAD16(wallt2 + (size_t)(rbb + srow) * 128 + k0 + schk * 8, Bs + rbb * 64);
        }
      }
    }
    __syncthreads();
    #pragma unroll
    for (int ko = 0; ko < 2; ko++) {
      bf16x8 af[3];
      #pragma unroll
      for (int mt = 0; mt < 3; mt++) {
        const int row = wm * 48 + mt * 16 + lr;
        const int pc = (ko * 4 + lq) ^ (lr & 7);
        af[mt] = __builtin_bit_cast(bf16x8, *(const uint4*)&As[row * 64 + pc * 8]);
      }
      #pragma unroll
      for (int nt = 0; nt < 5; nt++) {
        if (nt < 4 || wn == 0) {
          const int tid = wn + 2 * nt;  // wn0: 0,2,4,6,8 ; wn1: 1,3,5,7
          const int row = tid * 16 + lr;
          const int pc = (ko * 4 + lq) ^ (lr & 7);
          bf16x8 bfv = __builtin_bit_cast(bf16x8, *(const uint4*)&Bs[row * 64 + pc * 8]);
          #pragma unroll
          for (int mt = 0; mt < 3; mt++)
            acc[mt][nt] = __builtin_amdgcn_mfma_f32_16x16x32_bf16(af[mt], bfv, acc[mt][nt], 0, 0, 0);
        }
      }
    }
  }

  __syncthreads();                     // staging dead; write bf16 hp tile (146 stride)
  #pragma unroll
  for (int mt = 0; mt < 3; mt++)
    #pragma unroll
    for (int nt = 0; nt < 5; nt++)
      if (nt < 4 || wn == 0) {
        const int tid = wn + 2 * nt;
        #pragma unroll
        for (int i = 0; i < 4; i++) {
          const int rr = wm * 48 + mt * 16 + lq * 4 + i;
          const int cc = tid * 16 + lr;
          hps[rr * 146 + cc] = f2bf(acc[mt][nt][i]);
        }
      }
  __syncthreads();

  const int hh = lane >> 4;            // head of col pair (2l, 2l+1)

  for (int it = 0; it < 4; it++) {
    const int lb = w * 4 + it;
    const int b = blockIdx.x * 16 + lb;
    const unsigned short* hb = hps + lb * 6 * 146;

    float2 vm[6];
    float ein[6], ejn[6];
    #pragma unroll
    for (int m = 0; m < 6; m++) {
      unsigned int pk = *(const unsigned int*)&hb[m * 146 + lane * 2];
      vm[m].x = bf2f((unsigned short)(pk & 0xFFFFu));
      vm[m].y = bf2f((unsigned short)(pk >> 16));
      ein[m] = bf2f(hb[m * 146 + 128 + hh]);
      ejn[m] = bf2f(hb[m * 146 + 132 + hh]);
    }

    float g0[6], g1[6], zz[6];
    #pragma unroll
    for (int n = 0; n < 6; n++) {
      float ev[6]; float mx = -1e30f;
      #pragma unroll
      for (int m = 0; m < 6; m++) {
        float e = ein[n] + ejn[m];
        e = e > 0.f ? e : 0.2f * e;
        ev[m] = e; mx = fmaxf(mx, e);
      }
      float ss = 0.f;
      #pragma unroll
      for (int m = 0; m < 6; m++) { ev[m] = __expf(ev[m] - mx); ss += ev[m]; }
      const float inv = 1.0f / ss;
      float hn0 = 0.f, hn1 = 0.f;
      #pragma unroll
      for (int m = 0; m < 6; m++) {
        const float a = ev[m] * inv;
        hn0 += a * vm[m].x; hn1 += a * vm[m].y;
      }
      unsigned int xp = *(const unsigned int*)&xb[(size_t)b * 768 + n * 128 + lane * 2];
      float A0 = hn0 + bf2f((unsigned short)(xp & 0xFFFFu));
      float A1 = hn1 + bf2f((unsigned short)(xp >> 16));
      A0 = A0 > 0.f ? A0 : __expf(A0) - 1.0f;     // ELU, fast exp
      A1 = A1 > 0.f ? A1 : __expf(A1) - 1.0f;
      g0[n] = A0; g1[n] = A1;
      float zacc = A0 + A1;
      #pragma unroll
      for (int o = 32; o > 0; o >>= 1) zacc += __shfl_xor(zacc, o, 64);
      zz[n] = zacc * (1.0f / 128.0f);
    }

    float rr3[3];
    #pragma unroll
    for (int j = 0; j < 3; j++) {
      float a = se_b1[j];
      #pragma unroll
      for (int n = 0; n < 6; n++) a += zz[n] * se_w1[n * 3 + j];
      rr3[j] = fmaxf(a, 0.f);
    }
    float wse[6];
    #pragma unroll
    for (int n = 0; n < 6; n++) {
      float a = se_b2[n];
      #pragma unroll
      for (int j = 0; j < 3; j++) a += rr3[j] * se_w2[j * 6 + n];
      wse[n] = 1.0f / (1.0f + __expf(-a));
    }

    #pragma unroll
    for (int n = 0; n < 6; n++) {
      unsigned int pc = (unsigned int)f2bf(g0[n]) | ((unsigned int)f2bf(g1[n]) << 16);
      unsigned int ps = (unsigned int)f2bf(g0[n] * wse[n]) | ((unsigned int)f2bf(g1[n] * wse[n]) << 16);
      *(unsigned int*)&c[(size_t)b * 2688 + n * 128 + lane * 2]  = pc;
      *(unsigned int*)&sb[(size_t)b * 768 + n * 128 + lane * 2]  = ps;
    }
  }
}

// ---------------------------------------------------------------------------
// vid GEMM + pairs, LDS-transposed epilogue
// ---------------------------------------------------------------------------
__global__ __launch_bounds__(256)
void gemm_vid(const unsigned short* __restrict__ sbb, const unsigned short* __restrict__ biwt,
              unsigned short* __restrict__ c)
{
  const int z = blockIdx.z;
  const int m0 = blockIdx.y * 128;
  __shared__ __align__(16) unsigned short smem[128 * 130];
  unsigned short* As = smem;
  unsigned short* Bs = smem + 8192;
  const int t = threadIdx.x;
  const int lane = t & 63, w = t >> 6;
  const int wm = w & 1, wn = w >> 1;
  const int lr = lane & 15, lq = lane >> 4;

  floatx4 acc[4][4];
  #pragma unroll
  for (int a = 0; a < 4; a++)
    #pragma unroll
    for (int b = 0; b < 4; b++) acc[a][b] = (floatx4){0.f, 0.f, 0.f, 0.f};

  const int srow = lane >> 3;
  const int schk = (lane & 7) ^ srow;
  const unsigned short* Ag = sbb + (size_t)(m0 + w * 32 + srow) * 768 + z * 128 + schk * 8;
  const unsigned short* Bg = biwt + z * 16384 + (size_t)(w * 32 + srow) * 128 + schk * 8;
  unsigned short* AsW = As + w * 32 * 64;
  unsigned short* BsW = Bs + w * 32 * 64;

  for (int k0 = 0; k0 < 128; k0 += 64) {
    __syncthreads();
    #pragma unroll
    for (int q = 0; q < 4; q++) {
      ALOAD16(Ag + k0 + (size_t)(q * 8) * 768, AsW + q * 512);
      ALOAD16(Bg + k0 + (size_t)(q * 8) * 128, BsW + q * 512);
    }
    __syncthreads();
    #pragma unroll
    for (int ko = 0; ko < 2; ko++) {
      bf16x8 af[4], bfv[4];
      #pragma unroll
      for (int mt = 0; mt < 4; mt++) {
        const int row = wm * 64 + mt * 16 + lr;
        const int pc = (ko * 4 + lq) ^ (lr & 7);
        af[mt] = __builtin_bit_cast(bf16x8, *(const uint4*)&As[row * 64 + pc * 8]);
      }
      #pragma unroll
      for (int nt = 0; nt < 4; nt++) {
        const int row = wn * 64 + nt * 16 + lr;
        const int pc = (ko * 4 + lq) ^ (lr & 7);
        bfv[nt] = __builtin_bit_cast(bf16x8, *(const uint4*)&Bs[row * 64 + pc * 8]);
      }
      #pragma unroll
      for (int mt = 0; mt < 4; mt++)
        #pragma unroll
        for (int nt = 0; nt < 4; nt++)
          acc[mt][nt] = __builtin_amdgcn_mfma_f32_16x16x32_bf16(af[mt], bfv[nt], acc[mt][nt], 0, 0, 0);
    }
  }

  __syncthreads();
  #pragma unroll
  for (int mt = 0; mt < 4; mt++)
    #pragma unroll
    for (int nt = 0; nt < 4; nt++)
      #pragma unroll
      for (int i = 0; i < 4; i++) {
        const int rr = wm * 64 + mt * 16 + lq * 4 + i;
        const int cc = wn * 64 + nt * 16 + lr;
        smem[rr * 130 + cc] = f2bf(acc[mt][nt][i]);
      }
  __syncthreads();

  const int pb0[5] = {0, 5, 9, 12, 14};
  const int npairs = 5 - z;
  const int tot = 128 * 32 * npairs;
  for (int e = t; e < tot; e += 256) {
    const int g  = e & 31;
    const int rp = e >> 5;
    const int p  = rp % npairs;
    const int r  = rp / npairs;
    ushort4 vv = *(const ushort4*)&smem[r * 130 + g * 4];
    ushort4 sv = *(const ushort4*)&sbb[(size_t)(m0 + r) * 768 + (z + 1 + p) * 128 + g * 4];
    ushort4 o;
    o.x = f2bf(bf2f(vv.x) * bf2f(sv.x));
    o.y = f2bf(bf2f(vv.y) * bf2f(sv.y));
    o.z = f2bf(bf2f(vv.z) * bf2f(sv.z));
    o.w = f2bf(bf2f(vv.w) * bf2f(sv.w));
    *(ushort4*)&c[(size_t)(m0 + r) * 2688 + 768 + (size_t)(pb0[z] + p) * 128 + g * 4] = o;
  }
}

// ---------------------------------------------------------------------------
// Fused MLP2 + bn+gelu + final 256-dot + sigmoid -> out
// ---------------------------------------------------------------------------
__global__ __launch_bounds__(512)
void k_mlp2out(const unsigned short* __restrict__ A, const unsigned short* __restrict__ Bt,
               const float* __restrict__ b2v, const float* __restrict__ bng,
               const float* __restrict__ bnb, const float* __restrict__ w3,
               const float* __restrict__ b3, float* __restrict__ out)
{
  __shared__ __align__(16) char smem[40960];
  unsigned short* As = (unsigned short*)smem;
  unsigned short* Bs = (unsigned short*)(smem + 8192);
  unsigned short* h2s = (unsigned short*)smem;

  const int t = threadIdx.x, lane = t & 63, w = t >> 6;
  const int lr = lane & 15, lq = lane >> 4;
  const int m0 = blockIdx.x * 64;

  floatx4 acc[4][2];
  #pragma unroll
  for (int a = 0; a < 4; a++)
    #pragma unroll
    for (int b = 0; b < 2; b++) acc[a][b] = (floatx4){0.f, 0.f, 0.f, 0.f};

  const int srow = lane >> 3;
  const int schk = (lane & 7) ^ srow;
  const int rb0 = w * 40;

  for (int k0 = 0; k0 < 512; k0 += 64) {
    __syncthreads();
    #pragma unroll
    for (int q = 0; q < 5; q++) {
      const int rb = rb0 + q * 8;
      if (rb < 64) ALOAD16(A + (size_t)(m0 + rb + srow) * 512 + k0 + schk * 8, As + rb * 64);
      else { const int rbb = rb - 64; ALOAD16(Bt + (size_t)(rbb + srow) * 512 + k0 + schk * 8, Bs + rbb * 64); }
    }
    __syncthreads();
    #pragma unroll
    for (int ko = 0; ko < 2; ko++) {
      bf16x8 af[4], bfv[2];
      #pragma unroll
      for (int mt = 0; mt < 4; mt++) {
        const int row = mt * 16 + lr;
        const int pc = (ko * 4 + lq) ^ (lr & 7);
        af[mt] = __builtin_bit_cast(bf16x8, *(const uint4*)&As[row * 64 + pc * 8]);
      }
      #pragma unroll
      for (int nt = 0; nt < 2; nt++) {
        const int row = w * 32 + nt * 16 + lr;
        const int pc = (ko * 4 + lq) ^ (lr & 7);
        bfv[nt] = __builtin_bit_cast(bf16x8, *(const uint4*)&Bs[row * 64 + pc * 8]);
      }
      #pragma unroll
      for (int mt = 0; mt < 4; mt++)
        #pragma unroll
        for (int nt = 0; nt < 2; nt++)
          acc[mt][nt] = __builtin_amdgcn_mfma_f32_16x16x32_bf16(af[mt], bfv[nt], acc[mt][nt], 0, 0, 0);
    }
  }

  __syncthreads();
  #pragma unroll
  for (int mt = 0; mt < 4; mt++)
    #pragma unroll
    for (int nt = 0; nt < 2; nt++)
      #pragma unroll
      for (int i = 0; i < 4; i++) {
        const int rr = mt * 16 + lq * 4 + i;
        const int cc = w * 32 + nt * 16 + lr;
        float tt = acc[mt][nt][i] + b2v[cc];
        tt = tt * (bng[cc] * 0.9999950000374997f) + bnb[cc];
        h2s[rr * 264 + cc] = f2bf(gelu_exact(tt));
      }
  __syncthreads();

  const float4 w4 = *(const float4*)&w3[lane * 4];
  #pragma unroll
  for (int rr = 0; rr < 8; rr++) {
    const int r = w * 8 + rr;
    ushort4 v = *(const ushort4*)&h2s[r * 264 + lane * 4];
    float a = bf2f(v.x) * w4.x + bf2f(v.y) * w4.y + bf2f(v.z) * w4.z + bf2f(v.w) * w4.w;
    #pragma unroll
    for (int o = 32; o > 0; o >>= 1) a += __shfl_xor(a, o, 64);
    if (lane == 0) out[m0 + r] = 1.0f / (1.0f + __expf(-(a + b3[0])));
  }
}

// ---------------------------------------------------------------------------
// Workspace layout (bytes).  iembf8 (fp8, 11.7 MB) replaces bf16 table.
// ---------------------------------------------------------------------------
#define OFF_MMWT   0ull           // 32768
#define OFF_BIWT   65536ull       // 163840
#define OFF_W1T    229376ull      // 2752512
#define OFF_W2T    2981888ull     // 262144
#define OFF_IMMB   3244032ull     // 4194304
#define OFF_XB     7438336ull     // 25165824  (alias: h1 later)
#define OFF_SB     57769984ull    // 25165824
#define OFF_C      82935808ull    // 88080384
#define OFF_IEMB   179404800ull   // 11739904 (fp8)
#define OFF_WALLT2 191144704ull   // 36864 -> total 191181568

extern "C" void kernel_launch(void* const* d_in, const int* in_sizes, int n_in,
                              void* d_out, int out_size, void* d_ws, size_t ws_size,
                              hipStream_t stream)
{
  const int*   item_id  = (const int*)  d_in[0];
  const float* item_mm  = (const float*)d_in[1];
  const int*   likes    = (const int*)  d_in[2];
  const int*   views    = (const int*)  d_in[3];
  const int*   item_seq = (const int*)  d_in[4];
  const float* item_emb = (const float*)d_in[5];
  const float* cate_emb = (const float*)d_in[6];
  const float* mm_w     = (const float*)d_in[7];
  const float* mm_b     = (const float*)d_in[8];
  const float* ln_g     = (const float*)d_in[9];
  const float* ln_b     = (const float*)d_in[10];
  const float* gnn_W    = (const float*)d_in[11];
  const float* gnn_a    = (const float*)d_in[12];
  const float* se_w1    = (const float*)d_in[13];
  const float* se_b1    = (const float*)d_in[14];
  const float* se_w2    = (const float*)d_in[15];
  const float* se_b2    = (const float*)d_in[16];
  const float* bi_W     = (const float*)d_in[17];
  const float* mlp_w1   = (const float*)d_in[18];
  const float* mlp_b1   = (const float*)d_in[19];
  const float* bn1_g    = (const float*)d_in[20];
  const float* bn1_b    = (const float*)d_in[21];
  const float* mlp_w2   = (const float*)d_in[22];
  const float* mlp_b2   = (const float*)d_in[23];
  const float* bn2_g    = (const float*)d_in[24];
  const float* bn2_b    = (const float*)d_in[25];
  const float* mlp_w3   = (const float*)d_in[26];
  const float* mlp_b3   = (const float*)d_in[27];
  float* out = (float*)d_out;

  char* ws = (char*)d_ws;
  unsigned short* mmwt   = (unsigned short*)(ws + OFF_MMWT);
  unsigned short* biwt   = (unsigned short*)(ws + OFF_BIWT);
  unsigned short* w1t    = (unsigned short*)(ws + OFF_W1T);
  unsigned short* w2t    = (unsigned short*)(ws + OFF_W2T);
  unsigned short* immb   = (unsigned short*)(ws + OFF_IMMB);
  unsigned short* xb     = (unsigned short*)(ws + OFF_XB);
  unsigned short* sbb    = (unsigned short*)(ws + OFF_SB);
  unsigned short* cbuf   = (unsigned short*)(ws + OFF_C);
  unsigned short* h1b    = (unsigned short*)(ws + OFF_XB);   // alias: xb dead after k_hpatt
  unsigned char*  iembf8 = (unsigned char*) (ws + OFF_IEMB);
  unsigned short* wallt2 = (unsigned short*)(ws + OFF_WALLT2);

  // 1. merged packs + transposes (item_emb -> fp8 e4m3 table)
  k_prep<<<2440, 256, 0, stream>>>(gnn_W, gnn_a, item_mm, item_emb,
                                   mlp_w1, mlp_w2, bi_W, mm_w,
                                   wallt2, immb, iembf8, w1t, w2t, biwt, mmwt);
  // 2. merged feature build (fp8 gathers) + mm GEMM/LN/GELU
  k_featmm<<<2304, 512, 0, stream>>>(item_id, likes, views, item_seq, iembf8, cate_emb,
                                     immb, mmwt, mm_b, ln_g, ln_b, xb);
  // 3. fused hp GEMM (ei/ej in-GEMM) + attention + SE -> c[:, :768], sb
  k_hpatt<<<1024, 256, 0, stream>>>(xb, wallt2, se_w1, se_b1, se_w2, se_b2, cbuf, sbb);
  // 4. vid GEMM + pairs -> c[:, 768:]
  gemm_vid<<<dim3(1, 128, 5), 256, 0, stream>>>(sbb, biwt, cbuf);
  // 5. MLP1: h1 = gelu(bn1(c @ w1 + b1)), BK=64 (0-conflict layout)
  gemm_mlp1<<<dim3(4, 128), 512, 0, stream>>>(cbuf, w1t, h1b, mlp_b1, bn1_g, bn1_b);
  // 6. fused MLP2 + bn + gelu + dot(w3) + sigmoid -> out
  k_mlp2out<<<256, 512, 0, stream>>>(h1b, w2t, mlp_b2, bn2_g, bn2_b, mlp_w3, mlp_b3, out);
}